// Round 11
// baseline (492.855 us; speedup 1.0000x reference)
//
#include <hip/hip_runtime.h>
#include <math.h>

#define BATCH 4
#define SEQ   2048
#define TOK   (BATCH * SEQ)   // 8192
#define DM    1024
#define DP    1024
#define NH    16
#define DH    64
#define NLAB  8
#define QKV_C 3072
#define PADL  1152            // padded rows per label (9 x 128)
#define PROWS (NLAB * PADL)   // 9216
#define GP    72              // LDS row pitch for attn tiles (conflict-free)

typedef __attribute__((ext_vector_type(8))) short bf16x8;
typedef __attribute__((ext_vector_type(4))) float f32x4;

typedef const __attribute__((address_space(1))) void* gas_ptr;
typedef __attribute__((address_space(3))) void* las_ptr;

__device__ __forceinline__ short f2bf(float f) {
  union { float f; unsigned u; } v; v.f = f;
  unsigned r = v.u + 0x7FFF + ((v.u >> 16) & 1);   // RNE
  return (short)(r >> 16);
}

__device__ __forceinline__ unsigned cvt_pk_bf16(float lo, float hi) {
  unsigned r;
  asm("v_cvt_pk_bf16_f32 %0, %1, %2" : "=v"(r) : "v"(lo), "v"(hi));
  return r;
}

__device__ __forceinline__ float fast_exp2(float x) {
#if __has_builtin(__builtin_amdgcn_exp2f)
  return __builtin_amdgcn_exp2f(x);
#else
  return exp2f(x);
#endif
}

// ---------------- kernel 1: bucket tokens, build padded rowmap ----------------
__global__ void build_lists_k(const int* __restrict__ L, int* __restrict__ sorted,
                              int* __restrict__ rowmap) {
  __shared__ int cnt[NLAB], off[NLAB], cur[NLAB];
  int tid = threadIdx.x;
  if (tid < NLAB) cnt[tid] = 0;
  __syncthreads();
  for (int i = tid; i < TOK; i += 256) atomicAdd(&cnt[L[i]], 1);
  __syncthreads();
  if (tid == 0) {
    int o = 0;
    for (int l = 0; l < NLAB; ++l) { off[l] = o; cur[l] = o; o += cnt[l]; }
  }
  __syncthreads();
  for (int i = tid; i < TOK; i += 256) {
    int l = L[i];
    sorted[atomicAdd(&cur[l], 1)] = i;
  }
  __threadfence();
  __syncthreads();
  for (int p = tid; p < PROWS; p += 256) {
    int l = p / PADL, i = p - l * PADL;
    rowmap[p] = (i < cnt[l]) ? sorted[off[l] + i] : -1;
  }
}

// ---------------- kernel 1b: gather + fp32->bf16 X into padded row order ----
__global__ __launch_bounds__(256) void xg_k(const float* __restrict__ X,
                                            const int* __restrict__ rowmap,
                                            short* __restrict__ Xg) {
  int p = blockIdx.x;            // padded row 0..PROWS-1
  int t = rowmap[p];
  int c = threadIdx.x << 2;      // 4 elems per thread
  short* dst = Xg + (size_t)p * DM + c;
  if (t >= 0) {
    float4 v = *(const float4*)(X + (size_t)t * DM + c);
    short tmp[4] = { f2bf(v.x), f2bf(v.y), f2bf(v.z), f2bf(v.w) };
    *(uint2*)dst = *(uint2*)tmp;
  } else {
    uint2 z; z.x = 0u; z.y = 0u;
    *(uint2*)dst = z;
  }
}

// ---------------- kernel 2: fp32 -> bf16 transpose  [K][N] -> [N][K] ---------
__global__ __launch_bounds__(256) void wt_k(const float* __restrict__ src,
                                            short* __restrict__ dst,
                                            int K, int N) {
  __shared__ float Ts[64][65];   // [n][k]
  int m = blockIdx.z;
  src += (size_t)m * K * N;
  dst += (size_t)m * (size_t)N * K;
  int n0 = blockIdx.x * 64, k0 = blockIdx.y * 64;
  int tid = threadIdx.x;
  int r = tid >> 4;              // k within tile (16 rows/pass)
  int c = (tid & 15) << 2;       // n within tile
  #pragma unroll
  for (int it = 0; it < 4; ++it) {
    float4 v = *(const float4*)(src + (size_t)(k0 + r + it * 16) * N + n0 + c);
    Ts[c + 0][r + it * 16] = v.x;
    Ts[c + 1][r + it * 16] = v.y;
    Ts[c + 2][r + it * 16] = v.z;
    Ts[c + 3][r + it * 16] = v.w;
  }
  __syncthreads();
  int n = tid >> 2, ks = (tid & 3) << 4;
  short tmp[16];
  #pragma unroll
  for (int j = 0; j < 16; ++j) tmp[j] = f2bf(Ts[n][ks + j]);
  *(bf16x8*)(dst + (size_t)(n0 + n) * K + k0 + ks)     = *(bf16x8*)&tmp[0];
  *(bf16x8*)(dst + (size_t)(n0 + n) * K + k0 + ks + 8) = *(bf16x8*)&tmp[8];
}

// ---------------- kernel 3: label-routed QKV GEMM, bf16 MFMA ----------------
// v9: m99/m100-verified structure - DOUBLE-buffered linear LDS with
// global_load_lds width=16. Stage tile t+1 into the inactive buffer BEFORE
// computing tile t; single barrier per K-step (its vmcnt(0) drain is nearly
// free since the loads flew during the MFMA phase). 839-890 TF at this exact
// config in learn_hip. (v7's regression was single-buffer + full drain.)
__global__ __launch_bounds__(256) void qkv_mfma_k(
    const short* __restrict__ Xg, const short* __restrict__ Wt,
    const float* __restrict__ bqkv, const int* __restrict__ rowmap,
    short* __restrict__ qkvb) {
  __shared__ short As[2][128 * 64];
  __shared__ short Bs[2][128 * 64];
  // XCD swizzle: nwg = 24*72 = 1728, 216 per XCD (neutral but harmless)
  int flat = blockIdx.y * 24 + blockIdx.x;
  int swz  = (flat & 7) * 216 + (flat >> 3);
  int bx = swz % 24, by = swz / 24;
  int lab = by / 9;
  int pr0 = by * 128;
  int n0  = bx * 128;
  const short* W = Wt + (size_t)lab * QKV_C * DM;   // [3072][1024] bf16

  int tid  = threadIdx.x;
  int lane = tid & 63, w = tid >> 6;
  int wm = w >> 1, wn = w & 1;
  int col = lane & 15, quad = lane >> 4;

  // staging: wave w covers rows [w*32, w*32+32); per issue `it` the wave
  // writes 8 rows x 128B = 1KB linear LDS; lane l -> row +l/8, col (l%8)*8
  int lrow = lane >> 3;          // 0..7
  int lcol = (lane & 7) << 3;    // elems 0,8,..,56

  const short* aSrc = Xg + (size_t)(pr0 + w * 32 + lrow) * DM + lcol;
  const short* bSrc = W  + (size_t)(n0  + w * 32 + lrow) * DM + lcol;

  f32x4 acc[4][4];
  #pragma unroll
  for (int mi = 0; mi < 4; ++mi)
    #pragma unroll
    for (int ni = 0; ni < 4; ++ni) acc[mi][ni] = (f32x4){0.f, 0.f, 0.f, 0.f};

  // prologue: stage K-tile 0 into buffer 0
  #pragma unroll
  for (int it = 0; it < 4; ++it) {
    __builtin_amdgcn_global_load_lds(
        (gas_ptr)(aSrc + (size_t)(it * 8) * DM),
        (las_ptr)&As[0][(w * 32 + it * 8) * 64], 16, 0, 0);
    __builtin_amdgcn_global_load_lds(
        (gas_ptr)(bSrc + (size_t)(it * 8) * DM),
        (las_ptr)&Bs[0][(w * 32 + it * 8) * 64], 16, 0, 0);
  }
  __syncthreads();

  int cur = 0;
  for (int k0 = 0; k0 < DM; k0 += 64) {
    // ---- stage next tile into the inactive buffer (flies under MFMA) ----
    if (k0 + 64 < DM) {
      int nxt = cur ^ 1, kn = k0 + 64;
      #pragma unroll
      for (int it = 0; it < 4; ++it) {
        __builtin_amdgcn_global_load_lds(
            (gas_ptr)(aSrc + (size_t)(it * 8) * DM + kn),
            (las_ptr)&As[nxt][(w * 32 + it * 8) * 64], 16, 0, 0);
        __builtin_amdgcn_global_load_lds(
            (gas_ptr)(bSrc + (size_t)(it * 8) * DM + kn),
            (las_ptr)&Bs[nxt][(w * 32 + it * 8) * 64], 16, 0, 0);
      }
    }
    // ---- compute current buffer ----
    #pragma unroll
    for (int ks = 0; ks < 2; ++ks) {
      bf16x8 a[4], b[4];
      #pragma unroll
      for (int mi = 0; mi < 4; ++mi)
        a[mi] = *(bf16x8*)&As[cur][(wm * 64 + mi * 16 + col) * 64 + ks * 32 + (quad << 3)];
      #pragma unroll
      for (int ni = 0; ni < 4; ++ni)
        b[ni] = *(bf16x8*)&Bs[cur][(wn * 64 + ni * 16 + col) * 64 + ks * 32 + (quad << 3)];
      #pragma unroll
      for (int mi = 0; mi < 4; ++mi)
        #pragma unroll
        for (int ni = 0; ni < 4; ++ni)
          acc[mi][ni] = __builtin_amdgcn_mfma_f32_16x16x32_bf16(a[mi], b[ni], acc[mi][ni], 0, 0, 0);
    }
    __syncthreads();   // waits stage-writes (vmcnt) + all reads of cur done
    cur ^= 1;
  }

  // ---- epilogue: +bias, q-scale (1/8 * log2e for base-2 softmax), scatter ----
  float scale = (bx < 8) ? (0.125f * 1.44269504f) : 1.0f;
  const float* bias = bqkv + lab * QKV_C;
  #pragma unroll
  for (int mi = 0; mi < 4; ++mi) {
    #pragma unroll
    for (int r = 0; r < 4; ++r) {
      int prow = pr0 + wm * 64 + mi * 16 + (quad << 2) + r;
      int t2 = rowmap[prow];
      if (t2 < 0) continue;
      #pragma unroll
      for (int ni = 0; ni < 4; ++ni) {
        int gn = n0 + wn * 64 + ni * 16 + col;
        float v = (acc[mi][ni][r] + bias[gn]) * scale;
        qkvb[(size_t)t2 * QKV_C + gn] = f2bf(v);
      }
    }
  }
}

// ---------------- kernel 3b: V transpose  qkvb V-region -> VT[b][h][d][n] ----
__global__ __launch_bounds__(256) void vtb_k(const short* __restrict__ qkvb,
                                             short* __restrict__ VTg) {
  __shared__ short T[64 * GP];
  int n0 = blockIdx.x * 64, h = blockIdx.y, b = blockIdx.z;
  int tid = threadIdx.x;
  int r = tid >> 2, cb = tid & 3;
  {
    const short* src = qkvb + ((size_t)(b * SEQ + n0 + r)) * QKV_C + 2 * DP + h * DH + (cb << 4);
    int scc = ((cb + (r >> 4)) & 3) << 4;   // rotated chunk
    *(bf16x8*)&T[r * GP + scc]     = *(const bf16x8*)(src);
    *(bf16x8*)&T[r * GP + scc + 8] = *(const bf16x8*)(src + 8);
  }
  __syncthreads();
  int d = tid >> 2, nc = (tid & 3) << 4;
  int sc2 = (((d >> 4) + (nc >> 4)) & 3) << 4;
  short tmp[16];
  #pragma unroll
  for (int j = 0; j < 16; ++j) tmp[j] = T[(nc + j) * GP + sc2 + (d & 15)];
  short* dst = VTg + ((size_t)(b * NH + h) * DH + d) * SEQ + n0 + nc;
  *(bf16x8*)&dst[0] = *(bf16x8*)&tmp[0];
  *(bf16x8*)&dst[8] = *(bf16x8*)&tmp[8];
}

// ---------------- kernel 4: flash attention, bf16 MFMA, bf16 I/O -----------
// v6 (unchanged): swapped-operand softmax + deferred l-reduction + defer-max
// + setprio around MFMA clusters.
__global__ __launch_bounds__(256) void attn_k(short* __restrict__ qkvb,
                                              const short* __restrict__ VTg) {
  int qt = blockIdx.x, h = blockIdx.y, b = blockIdx.z;
  __shared__ short Ks[64 * GP];
  __shared__ short VT[64 * GP];    // VT[d][kv]
  __shared__ short Ps[128 * GP];   // [q 0..127][kv 0..63]

  int tid  = threadIdx.x;
  int lane = tid & 63;
  int w    = tid >> 6;
  int col  = lane & 15;
  int quad = lane >> 4;

  size_t rowbase = (size_t)b * SEQ;
  int hoff = h * DH;
  int sr = tid >> 2;            // staging row 0..63
  int sc = (tid & 3) << 4;      // staging col 0,16,32,48

  const short* ksrc = qkvb + (rowbase + sr) * QKV_C + DP + hoff + sc;
  const short* vsrc = VTg + ((size_t)(b * NH + h) * DH + sr) * SEQ + sc;

  // ---- Q B-fragments: direct global load, loop-invariant (2 strips) ----
  bf16x8 qf0[2], qf1[2];
  {
    const short* q0 = qkvb + (rowbase + qt * 128 + (w << 4) + col) * QKV_C + hoff + (quad << 3);
    const short* q1 = q0 + (size_t)64 * QKV_C;
    qf0[0] = *(const bf16x8*)(q0);
    qf0[1] = *(const bf16x8*)(q0 + 32);
    qf1[0] = *(const bf16x8*)(q1);
    qf1[1] = *(const bf16x8*)(q1 + 32);
  }

  // ---- preload kv tile 0 ----
  {
    bf16x8 ka = *(const bf16x8*)(ksrc);
    bf16x8 kb = *(const bf16x8*)(ksrc + 8);
    bf16x8 va = *(const bf16x8*)(vsrc);
    bf16x8 vb = *(const bf16x8*)(vsrc + 8);
    *(bf16x8*)&Ks[sr * GP + sc]     = ka;
    *(bf16x8*)&Ks[sr * GP + sc + 8] = kb;
    *(bf16x8*)&VT[sr * GP + sc]     = va;
    *(bf16x8*)&VT[sr * GP + sc + 8] = vb;
  }
  __syncthreads();

  float m_0 = -1e30f, l_0 = 0.f, m_1 = -1e30f, l_1 = 0.f;
  f32x4 o0[4], o1[4];   // O^T: lane holds O[q=col][d = nd*16 + quad*4 + r]
  #pragma unroll
  for (int nd = 0; nd < 4; ++nd) {
    o0[nd] = (f32x4){0.f, 0.f, 0.f, 0.f};
    o1[nd] = (f32x4){0.f, 0.f, 0.f, 0.f};
  }

  short* ps0 = &Ps[((w << 4) + col) * GP];
  short* ps1 = &Ps[(64 + (w << 4) + col) * GP];

  auto softmax_strip = [&](f32x4* s, float& m_, float& l_, f32x4* o, short* psrow) {
    f32x4 t0, t1;
    #pragma unroll
    for (int i = 0; i < 4; ++i) { t0[i] = fmaxf(s[0][i], s[1][i]); t1[i] = fmaxf(s[2][i], s[3][i]); }
    #pragma unroll
    for (int i = 0; i < 4; ++i) t0[i] = fmaxf(t0[i], t1[i]);
    float mx = fmaxf(fmaxf(t0[0], t0[1]), fmaxf(t0[2], t0[3]));
    if (!__all(mx - m_ <= 8.f)) {
      float mxr = fmaxf(mx, __shfl_xor(mx, 16));
      mxr = fmaxf(mxr, __shfl_xor(mxr, 32));
      float mnew  = fmaxf(m_, mxr);
      float alpha = fast_exp2(m_ - mnew);
      l_ *= alpha;
      #pragma unroll
      for (int nd = 0; nd < 4; ++nd)
        #pragma unroll
        for (int r = 0; r < 4; ++r) o[nd][r] *= alpha;
      m_ = mnew;
    }
    float p[4][4];
    #pragma unroll
    for (int nj = 0; nj < 4; ++nj)
      #pragma unroll
      for (int r = 0; r < 4; ++r) p[nj][r] = fast_exp2(s[nj][r] - m_);
    float rs = 0.f;
    #pragma unroll
    for (int nj = 0; nj < 4; ++nj)
      rs += (p[nj][0] + p[nj][1]) + (p[nj][2] + p[nj][3]);
    l_ += rs;            // per-lane partial; cross-quad reduce at epilogue
    #pragma unroll
    for (int nj = 0; nj < 4; ++nj) {
      uint2 u;
      u.x = cvt_pk_bf16(p[nj][0], p[nj][1]);
      u.y = cvt_pk_bf16(p[nj][2], p[nj][3]);
      *(uint2*)&psrow[nj * 16 + (quad << 2)] = u;
    }
  };

  auto compute_tile = [&]() {
    f32x4 s0[4], s1[4];
    #pragma unroll
    for (int nj = 0; nj < 4; ++nj) {
      s0[nj] = (f32x4){0.f, 0.f, 0.f, 0.f};
      s1[nj] = (f32x4){0.f, 0.f, 0.f, 0.f};
    }
    __builtin_amdgcn_s_setprio(1);
    #pragma unroll
    for (int ks = 0; ks < 2; ++ks) {
      #pragma unroll
      for (int nj = 0; nj < 4; ++nj) {
        bf16x8 aK = *(bf16x8*)&Ks[((nj << 4) + col) * GP + (ks << 5) + (quad << 3)];
        s0[nj] = __builtin_amdgcn_mfma_f32_16x16x32_bf16(aK, qf0[ks], s0[nj], 0, 0, 0);
        s1[nj] = __builtin_amdgcn_mfma_f32_16x16x32_bf16(aK, qf1[ks], s1[nj], 0, 0, 0);
      }
    }
    __builtin_amdgcn_s_setprio(0);
    softmax_strip(s0, m_0, l_0, o0, ps0);
    softmax_strip(s1, m_1, l_1, o1, ps1);
    __builtin_amdgcn_s_setprio(1);
    #pragma unroll
    for (int ks = 0; ks < 2; ++ks) {
      bf16x8 bP0 = *(bf16x8*)&ps0[(ks << 5) + (quad << 3)];
      bf16x8 bP1 = *(bf16x8*)&ps1[(ks << 5) + (quad << 3)];
      #pragma unroll
      for (int nd = 0; nd < 4; ++nd) {
        bf16x8 aV = *(bf16x8*)&VT[((nd << 4) + col) * GP + (ks << 5) + (quad << 3)];
        o0[nd] = __builtin_amdgcn_mfma_f32_16x16x32_bf16(aV, bP0, o0[nd], 0, 0, 0);
        o1[nd] = __builtin_amdgcn_mfma_f32_16x16x32_bf16(aV, bP1, o1[nd], 0, 0, 0);
      }
    }
    __builtin_amdgcn_s_setprio(0);
  };

  for (int kt = 0; kt < SEQ / 64 - 1; ++kt) {
    const short* kn = ksrc + (size_t)(kt + 1) * 64 * QKV_C;
    const short* vn = vsrc + (size_t)(kt + 1) * 64;
    bf16x8 ka = *(const bf16x8*)(kn);
    bf16x8 kb = *(const bf16x8*)(kn + 8);
    bf16x8 va = *(const bf16x8*)(vn);
    bf16x8 vb = *(const bf16x8*)(vn + 8);

    compute_tile();
    __syncthreads();                   // all waves done reading Ks/VT
    *(bf16x8*)&Ks[sr * GP + sc]     = ka;
    *(bf16x8*)&Ks[sr * GP + sc + 8] = kb;
    *(bf16x8*)&VT[sr * GP + sc]     = va;
    *(bf16x8*)&VT[sr * GP + sc + 8] = vb;
    __syncthreads();                   // next tile staged
  }
  compute_tile();                      // last tile

  // ---- epilogue: final cross-quad l reduce, O/l packed 8B stores ----
  float lt0 = l_0 + __shfl_xor(l_0, 16);
  lt0 += __shfl_xor(lt0, 32);
  float lt1 = l_1 + __shfl_xor(l_1, 16);
  lt1 += __shfl_xor(lt1, 32);
  #pragma unroll
  for (int s = 0; s < 2; ++s) {
    float inv = 1.f / (s ? lt1 : lt0);
    f32x4* o = s ? o1 : o0;
    size_t row = rowbase + qt * 128 + s * 64 + (w << 4) + col;
    #pragma unroll
    for (int nd = 0; nd < 4; ++nd) {
      uint2 u;
      u.x = cvt_pk_bf16(o[nd][0] * inv, o[nd][1] * inv);
      u.y = cvt_pk_bf16(o[nd][2] * inv, o[nd][3] * inv);
      *(uint2*)(qkvb + row * QKV_C + hoff + (nd << 4) + (quad << 2)) = u;
    }
  }
}

// ---------------- kernel 5: output projection, bf16 MFMA ----------------
// v9: same dbuf global_load_lds structure as qkv_mfma_k.
__global__ __launch_bounds__(256) void proj_mfma_k(
    const short* __restrict__ Ab, const short* __restrict__ Wt,
    const float* __restrict__ bias, float* __restrict__ out) {
  __shared__ short As[2][128 * 64];
  __shared__ short Bs[2][128 * 64];
  int flat = blockIdx.y * 8 + blockIdx.x;
  int swz  = (flat & 7) * 64 + (flat >> 3);
  int n0 = (swz & 7) * 128, m0 = (swz >> 3) * 128;

  int tid  = threadIdx.x;
  int lane = tid & 63, w = tid >> 6;
  int wm = w >> 1, wn = w & 1;
  int col = lane & 15, quad = lane >> 4;

  int lrow = lane >> 3;          // 0..7
  int lcol = (lane & 7) << 3;

  const short* aSrc = Ab + (size_t)(m0 + w * 32 + lrow) * QKV_C + lcol;
  const short* bSrc = Wt + (size_t)(n0 + w * 32 + lrow) * DP + lcol;

  f32x4 acc[4][4];
  #pragma unroll
  for (int mi = 0; mi < 4; ++mi)
    #pragma unroll
    for (int ni = 0; ni < 4; ++ni) acc[mi][ni] = (f32x4){0.f, 0.f, 0.f, 0.f};

  #pragma unroll
  for (int it = 0; it < 4; ++it) {
    __builtin_amdgcn_global_load_lds(
        (gas_ptr)(aSrc + (size_t)(it * 8) * QKV_C),
        (las_ptr)&As[0][(w * 32 + it * 8) * 64], 16, 0, 0);
    __builtin_amdgcn_global_load_lds(
        (gas_ptr)(bSrc + (size_t)(it * 8) * DP),
        (las_ptr)&Bs[0][(w * 32 + it * 8) * 64], 16, 0, 0);
  }
  __syncthreads();

  int cur = 0;
  for (int k0 = 0; k0 < DP; k0 += 64) {
    if (k0 + 64 < DP) {
      int nxt = cur ^ 1, kn = k0 + 64;
      #pragma unroll
      for (int it = 0; it < 4; ++it) {
        __builtin_amdgcn_global_load_lds(
            (gas_ptr)(aSrc + (size_t)(it * 8) * QKV_C + kn),
            (las_ptr)&As[nxt][(w * 32 + it * 8) * 64], 16, 0, 0);
        __builtin_amdgcn_global_load_lds(
            (gas_ptr)(bSrc + (size_t)(it * 8) * DP + kn),
            (las_ptr)&Bs[nxt][(w * 32 + it * 8) * 64], 16, 0, 0);
      }
    }
    #pragma unroll
    for (int ks = 0; ks < 2; ++ks) {
      bf16x8 a[4], b[4];
      #pragma unroll
      for (int mi = 0; mi < 4; ++mi)
        a[mi] = *(bf16x8*)&As[cur][(wm * 64 + mi * 16 + col) * 64 + ks * 32 + (quad << 3)];
      #pragma unroll
      for (int ni = 0; ni < 4; ++ni)
        b[ni] = *(bf16x8*)&Bs[cur][(wn * 64 + ni * 16 + col) * 64 + ks * 32 + (quad << 3)];
      #pragma unroll
      for (int mi = 0; mi < 4; ++mi)
        #pragma unroll
        for (int ni = 0; ni < 4; ++ni)
          acc[mi][ni] = __builtin_amdgcn_mfma_f32_16x16x32_bf16(a[mi], b[ni], acc[mi][ni], 0, 0, 0);
    }
    __syncthreads();
    cur ^= 1;
  }

  #pragma unroll
  for (int mi = 0; mi < 4; ++mi) {
    #pragma unroll
    for (int r = 0; r < 4; ++r) {
      int m = m0 + wm * 64 + mi * 16 + (quad << 2) + r;
      #pragma unroll
      for (int ni = 0; ni < 4; ++ni) {
        int gn = n0 + wn * 64 + ni * 16 + col;
        out[(size_t)m * DM + gn] = acc[mi][ni][r] + bias[gn];
      }
    }
  }
}

// ---------------- launch ----------------
extern "C" void kernel_launch(void* const* d_in, const int* in_sizes, int n_in,
                              void* d_out, int out_size, void* d_ws, size_t ws_size,
                              hipStream_t stream) {
  (void)in_sizes; (void)n_in; (void)out_size; (void)ws_size;
  const float* X     = (const float*)d_in[0];
  const int*   L     = (const int*)d_in[1];
  const float* Wqkv  = (const float*)d_in[2];
  const float* bqkv  = (const float*)d_in[3];
  const float* Wproj = (const float*)d_in[4];
  const float* bproj = (const float*)d_in[5];
  float* out = (float*)d_out;

  char* ws = (char*)d_ws;
  short* qkvb    = (short*)ws;                                   // 8192x3072 bf16 (50.3 MB)
  short* Wqkv_t  = (short*)(ws + (size_t)TOK * QKV_C * 2);       // 8x3072x1024 bf16 (50.3 MB)
  short* Wproj_t = (short*)(ws + (size_t)TOK * QKV_C * 2
                               + (size_t)NLAB * QKV_C * DM * 2); // 1024x1024 bf16 (2.1 MB)
  int* sorted = (int*)((char*)Wproj_t + (size_t)DP * DM * 2);
  int* rowmap = sorted + TOK;
  short* Xg = (short*)(rowmap + PROWS);                          // 9216x1024 bf16 (18.9 MB)
  // VT[b][h][d][n] bf16 (16.8 MB) aliases Wqkv_t, which is dead after
  // qkv_mfma_k and re-built by wt_k at the start of each iteration.
  short* VTg = Wqkv_t;

  build_lists_k<<<dim3(1), dim3(256), 0, stream>>>(L, sorted, rowmap);
  xg_k<<<dim3(PROWS), dim3(256), 0, stream>>>(X, rowmap, Xg);
  wt_k<<<dim3(QKV_C / 64, DM / 64, NLAB), dim3(256), 0, stream>>>(Wqkv, Wqkv_t, DM, QKV_C);
  wt_k<<<dim3(DM / 64, DP / 64, 1), dim3(256), 0, stream>>>(Wproj, Wproj_t, DP, DM);
  qkv_mfma_k<<<dim3(QKV_C / 128, PROWS / 128), dim3(256), 0, stream>>>(
      Xg, Wqkv_t, bqkv, rowmap, qkvb);
  vtb_k<<<dim3(SEQ / 64, NH, BATCH), dim3(256), 0, stream>>>(qkvb, VTg);
  attn_k<<<dim3(SEQ / 128, NH, BATCH), dim3(256), 0, stream>>>(qkvb, VTg);
  proj_mfma_k<<<dim3(DM / 128, TOK / 128), dim3(256), 0, stream>>>(
      qkvb, Wproj_t, bproj, out);
}

// Round 12
// 468.788 us; speedup vs baseline: 1.0513x; 1.0513x over previous
//
#include <hip/hip_runtime.h>
#include <math.h>

#define BATCH 4
#define SEQ   2048
#define TOK   (BATCH * SEQ)   // 8192
#define DM    1024
#define DP    1024
#define NH    16
#define DH    64
#define NLAB  8
#define QKV_C 3072
#define PADL  1152            // padded rows per label (9 x 128)
#define PROWS (NLAB * PADL)   // 9216
#define GP    72              // LDS row pitch (bf16 elems) - verified conflict-free

typedef __attribute__((ext_vector_type(8))) short bf16x8;
typedef __attribute__((ext_vector_type(4))) float f32x4;

__device__ __forceinline__ short f2bf(float f) {
  union { float f; unsigned u; } v; v.f = f;
  unsigned r = v.u + 0x7FFF + ((v.u >> 16) & 1);   // RNE
  return (short)(r >> 16);
}

__device__ __forceinline__ unsigned cvt_pk_bf16(float lo, float hi) {
  unsigned r;
  asm("v_cvt_pk_bf16_f32 %0, %1, %2" : "=v"(r) : "v"(lo), "v"(hi));
  return r;
}

__device__ __forceinline__ float fast_exp2(float x) {
#if __has_builtin(__builtin_amdgcn_exp2f)
  return __builtin_amdgcn_exp2f(x);
#else
  return exp2f(x);
#endif
}

// ---------------- kernel 1: bucket tokens, build padded rowmap ----------------
__global__ void build_lists_k(const int* __restrict__ L, int* __restrict__ sorted,
                              int* __restrict__ rowmap) {
  __shared__ int cnt[NLAB], off[NLAB], cur[NLAB];
  int tid = threadIdx.x;
  if (tid < NLAB) cnt[tid] = 0;
  __syncthreads();
  for (int i = tid; i < TOK; i += 256) atomicAdd(&cnt[L[i]], 1);
  __syncthreads();
  if (tid == 0) {
    int o = 0;
    for (int l = 0; l < NLAB; ++l) { off[l] = o; cur[l] = o; o += cnt[l]; }
  }
  __syncthreads();
  for (int i = tid; i < TOK; i += 256) {
    int l = L[i];
    sorted[atomicAdd(&cur[l], 1)] = i;
  }
  __threadfence();
  __syncthreads();
  for (int p = tid; p < PROWS; p += 256) {
    int l = p / PADL, i = p - l * PADL;
    rowmap[p] = (i < cnt[l]) ? sorted[off[l] + i] : -1;
  }
}

// ---------------- kernel 1b: gather + fp32->bf16 X into padded row order ----
__global__ __launch_bounds__(256) void xg_k(const float* __restrict__ X,
                                            const int* __restrict__ rowmap,
                                            short* __restrict__ Xg) {
  int p = blockIdx.x;            // padded row 0..PROWS-1
  int t = rowmap[p];
  int c = threadIdx.x << 2;      // 4 elems per thread
  short* dst = Xg + (size_t)p * DM + c;
  if (t >= 0) {
    float4 v = *(const float4*)(X + (size_t)t * DM + c);
    short tmp[4] = { f2bf(v.x), f2bf(v.y), f2bf(v.z), f2bf(v.w) };
    *(uint2*)dst = *(uint2*)tmp;
  } else {
    uint2 z; z.x = 0u; z.y = 0u;
    *(uint2*)dst = z;
  }
}

// ---------------- kernel 2: fp32 -> bf16 transpose  [K][N] -> [N][K] ---------
__global__ __launch_bounds__(256) void wt_k(const float* __restrict__ src,
                                            short* __restrict__ dst,
                                            int K, int N) {
  __shared__ float Ts[64][65];   // [n][k]
  int m = blockIdx.z;
  src += (size_t)m * K * N;
  dst += (size_t)m * (size_t)N * K;
  int n0 = blockIdx.x * 64, k0 = blockIdx.y * 64;
  int tid = threadIdx.x;
  int r = tid >> 4;              // k within tile (16 rows/pass)
  int c = (tid & 15) << 2;       // n within tile
  #pragma unroll
  for (int it = 0; it < 4; ++it) {
    float4 v = *(const float4*)(src + (size_t)(k0 + r + it * 16) * N + n0 + c);
    Ts[c + 0][r + it * 16] = v.x;
    Ts[c + 1][r + it * 16] = v.y;
    Ts[c + 2][r + it * 16] = v.z;
    Ts[c + 3][r + it * 16] = v.w;
  }
  __syncthreads();
  int n = tid >> 2, ks = (tid & 3) << 4;
  short tmp[16];
  #pragma unroll
  for (int j = 0; j < 16; ++j) tmp[j] = f2bf(Ts[n][ks + j]);
  *(bf16x8*)(dst + (size_t)(n0 + n) * K + k0 + ks)     = *(bf16x8*)&tmp[0];
  *(bf16x8*)(dst + (size_t)(n0 + n) * K + k0 + ks + 8) = *(bf16x8*)&tmp[8];
}

// ---------------- kernel 3: label-routed QKV GEMM, bf16 MFMA ----------------
// v10: v8 reg-prefetch structure with DEPTH-2 prefetch: two reg sets (rA =
// even tiles, rB = odd tiles); a load issued at iteration k is consumed at
// k+2, giving ~2 full iterations (~700 cyc) for HBM/L2 latency to hide.
__global__ __launch_bounds__(256) void qkv_mfma_k(
    const short* __restrict__ Xg, const short* __restrict__ Wt,
    const float* __restrict__ bqkv, const int* __restrict__ rowmap,
    short* __restrict__ qkvb) {
  __shared__ short As[128 * GP];
  __shared__ short Bs[128 * GP];
  // XCD swizzle: nwg = 24*72 = 1728, 216 per XCD (neutral but harmless)
  int flat = blockIdx.y * 24 + blockIdx.x;
  int swz  = (flat & 7) * 216 + (flat >> 3);
  int bx = swz % 24, by = swz / 24;
  int lab = by / 9;
  int pr0 = by * 128;
  int n0  = bx * 128;
  const short* W = Wt + (size_t)lab * QKV_C * DM;   // [3072][1024] bf16

  int tid  = threadIdx.x;
  int lane = tid & 63, w = tid >> 6;
  int wm = w >> 1, wn = w & 1;
  int col = lane & 15, quad = lane >> 4;

  int srow = tid >> 2;            // staging row 0..63 (+64 on 2nd rep)
  int scol = (tid & 3) << 4;      // staging col 0,16,32,48

  const short* a0 = Xg + (size_t)(pr0 + srow) * DM + scol;
  const short* a1 = Xg + (size_t)(pr0 + 64 + srow) * DM + scol;
  const short* b0 = W + (size_t)(n0 + srow) * DM + scol;
  const short* b1 = W + (size_t)(n0 + 64 + srow) * DM + scol;

  f32x4 acc[4][4];
  #pragma unroll
  for (int mi = 0; mi < 4; ++mi)
    #pragma unroll
    for (int ni = 0; ni < 4; ++ni) acc[mi][ni] = (f32x4){0.f, 0.f, 0.f, 0.f};

  auto loadT = [&](bf16x8 (&r)[8], int k) {
    r[0] = *(const bf16x8*)(a0 + k);     r[1] = *(const bf16x8*)(a0 + k + 8);
    r[2] = *(const bf16x8*)(a1 + k);     r[3] = *(const bf16x8*)(a1 + k + 8);
    r[4] = *(const bf16x8*)(b0 + k);     r[5] = *(const bf16x8*)(b0 + k + 8);
    r[6] = *(const bf16x8*)(b1 + k);     r[7] = *(const bf16x8*)(b1 + k + 8);
  };
  auto stageT = [&](bf16x8 (&r)[8]) {
    *(bf16x8*)&As[srow * GP + scol]            = r[0];
    *(bf16x8*)&As[srow * GP + scol + 8]        = r[1];
    *(bf16x8*)&As[(64 + srow) * GP + scol]     = r[2];
    *(bf16x8*)&As[(64 + srow) * GP + scol + 8] = r[3];
    *(bf16x8*)&Bs[srow * GP + scol]            = r[4];
    *(bf16x8*)&Bs[srow * GP + scol + 8]        = r[5];
    *(bf16x8*)&Bs[(64 + srow) * GP + scol]     = r[6];
    *(bf16x8*)&Bs[(64 + srow) * GP + scol + 8] = r[7];
  };
  auto mfmaT = [&]() {
    #pragma unroll
    for (int ks = 0; ks < 2; ++ks) {
      bf16x8 a[4], b[4];
      #pragma unroll
      for (int mi = 0; mi < 4; ++mi)
        a[mi] = *(bf16x8*)&As[(wm * 64 + mi * 16 + col) * GP + ks * 32 + (quad << 3)];
      #pragma unroll
      for (int ni = 0; ni < 4; ++ni)
        b[ni] = *(bf16x8*)&Bs[(wn * 64 + ni * 16 + col) * GP + ks * 32 + (quad << 3)];
      #pragma unroll
      for (int mi = 0; mi < 4; ++mi)
        #pragma unroll
        for (int ni = 0; ni < 4; ++ni)
          acc[mi][ni] = __builtin_amdgcn_mfma_f32_16x16x32_bf16(a[mi], b[ni], acc[mi][ni], 0, 0, 0);
    }
  };

  bf16x8 rA[8], rB[8];
  loadT(rA, 0);            // tile 0 (even)
  loadT(rB, 64);           // tile 1 (odd)
  for (int k0 = 0; k0 < DM; k0 += 128) {
    stageT(rA);
    __syncthreads();
    if (k0 + 128 < DM) loadT(rA, k0 + 128);   // even tile k+2 in flight
    mfmaT();
    __syncthreads();
    stageT(rB);
    __syncthreads();
    if (k0 + 192 < DM) loadT(rB, k0 + 192);   // odd tile k+2 in flight
    mfmaT();
    __syncthreads();
  }

  // ---- epilogue: +bias, q-scale (1/8 * log2e for base-2 softmax), scatter ----
  float scale = (bx < 8) ? (0.125f * 1.44269504f) : 1.0f;
  const float* bias = bqkv + lab * QKV_C;
  #pragma unroll
  for (int mi = 0; mi < 4; ++mi) {
    #pragma unroll
    for (int r = 0; r < 4; ++r) {
      int prow = pr0 + wm * 64 + mi * 16 + (quad << 2) + r;
      int t2 = rowmap[prow];
      if (t2 < 0) continue;
      #pragma unroll
      for (int ni = 0; ni < 4; ++ni) {
        int gn = n0 + wn * 64 + ni * 16 + col;
        float v = (acc[mi][ni][r] + bias[gn]) * scale;
        qkvb[(size_t)t2 * QKV_C + gn] = f2bf(v);
      }
    }
  }
}

// ---------------- kernel 3b: V transpose  qkvb V-region -> VT[b][h][d][n] ----
__global__ __launch_bounds__(256) void vtb_k(const short* __restrict__ qkvb,
                                             short* __restrict__ VTg) {
  __shared__ short T[64 * GP];
  int n0 = blockIdx.x * 64, h = blockIdx.y, b = blockIdx.z;
  int tid = threadIdx.x;
  int r = tid >> 2, cb = tid & 3;
  {
    const short* src = qkvb + ((size_t)(b * SEQ + n0 + r)) * QKV_C + 2 * DP + h * DH + (cb << 4);
    int scc = ((cb + (r >> 4)) & 3) << 4;   // rotated chunk
    *(bf16x8*)&T[r * GP + scc]     = *(const bf16x8*)(src);
    *(bf16x8*)&T[r * GP + scc + 8] = *(const bf16x8*)(src + 8);
  }
  __syncthreads();
  int d = tid >> 2, nc = (tid & 3) << 4;
  int sc2 = (((d >> 4) + (nc >> 4)) & 3) << 4;
  short tmp[16];
  #pragma unroll
  for (int j = 0; j < 16; ++j) tmp[j] = T[(nc + j) * GP + sc2 + (d & 15)];
  short* dst = VTg + ((size_t)(b * NH + h) * DH + d) * SEQ + n0 + nc;
  *(bf16x8*)&dst[0] = *(bf16x8*)&tmp[0];
  *(bf16x8*)&dst[8] = *(bf16x8*)&tmp[8];
}

// ---------------- kernel 4: flash attention, bf16 MFMA, bf16 I/O -----------
// v6 (unchanged): swapped-operand softmax + deferred l-reduction + defer-max
// + setprio around MFMA clusters.
__global__ __launch_bounds__(256) void attn_k(short* __restrict__ qkvb,
                                              const short* __restrict__ VTg) {
  int qt = blockIdx.x, h = blockIdx.y, b = blockIdx.z;
  __shared__ short Ks[64 * GP];
  __shared__ short VT[64 * GP];    // VT[d][kv]
  __shared__ short Ps[128 * GP];   // [q 0..127][kv 0..63]

  int tid  = threadIdx.x;
  int lane = tid & 63;
  int w    = tid >> 6;
  int col  = lane & 15;
  int quad = lane >> 4;

  size_t rowbase = (size_t)b * SEQ;
  int hoff = h * DH;
  int sr = tid >> 2;            // staging row 0..63
  int sc = (tid & 3) << 4;      // staging col 0,16,32,48

  const short* ksrc = qkvb + (rowbase + sr) * QKV_C + DP + hoff + sc;
  const short* vsrc = VTg + ((size_t)(b * NH + h) * DH + sr) * SEQ + sc;

  // ---- Q B-fragments: direct global load, loop-invariant (2 strips) ----
  bf16x8 qf0[2], qf1[2];
  {
    const short* q0 = qkvb + (rowbase + qt * 128 + (w << 4) + col) * QKV_C + hoff + (quad << 3);
    const short* q1 = q0 + (size_t)64 * QKV_C;
    qf0[0] = *(const bf16x8*)(q0);
    qf0[1] = *(const bf16x8*)(q0 + 32);
    qf1[0] = *(const bf16x8*)(q1);
    qf1[1] = *(const bf16x8*)(q1 + 32);
  }

  // ---- preload kv tile 0 ----
  {
    bf16x8 ka = *(const bf16x8*)(ksrc);
    bf16x8 kb = *(const bf16x8*)(ksrc + 8);
    bf16x8 va = *(const bf16x8*)(vsrc);
    bf16x8 vb = *(const bf16x8*)(vsrc + 8);
    *(bf16x8*)&Ks[sr * GP + sc]     = ka;
    *(bf16x8*)&Ks[sr * GP + sc + 8] = kb;
    *(bf16x8*)&VT[sr * GP + sc]     = va;
    *(bf16x8*)&VT[sr * GP + sc + 8] = vb;
  }
  __syncthreads();

  float m_0 = -1e30f, l_0 = 0.f, m_1 = -1e30f, l_1 = 0.f;
  f32x4 o0[4], o1[4];   // O^T: lane holds O[q=col][d = nd*16 + quad*4 + r]
  #pragma unroll
  for (int nd = 0; nd < 4; ++nd) {
    o0[nd] = (f32x4){0.f, 0.f, 0.f, 0.f};
    o1[nd] = (f32x4){0.f, 0.f, 0.f, 0.f};
  }

  short* ps0 = &Ps[((w << 4) + col) * GP];
  short* ps1 = &Ps[(64 + (w << 4) + col) * GP];

  auto softmax_strip = [&](f32x4* s, float& m_, float& l_, f32x4* o, short* psrow) {
    f32x4 t0, t1;
    #pragma unroll
    for (int i = 0; i < 4; ++i) { t0[i] = fmaxf(s[0][i], s[1][i]); t1[i] = fmaxf(s[2][i], s[3][i]); }
    #pragma unroll
    for (int i = 0; i < 4; ++i) t0[i] = fmaxf(t0[i], t1[i]);
    float mx = fmaxf(fmaxf(t0[0], t0[1]), fmaxf(t0[2], t0[3]));
    if (!__all(mx - m_ <= 8.f)) {
      float mxr = fmaxf(mx, __shfl_xor(mx, 16));
      mxr = fmaxf(mxr, __shfl_xor(mxr, 32));
      float mnew  = fmaxf(m_, mxr);
      float alpha = fast_exp2(m_ - mnew);
      l_ *= alpha;
      #pragma unroll
      for (int nd = 0; nd < 4; ++nd)
        #pragma unroll
        for (int r = 0; r < 4; ++r) o[nd][r] *= alpha;
      m_ = mnew;
    }
    float p[4][4];
    #pragma unroll
    for (int nj = 0; nj < 4; ++nj)
      #pragma unroll
      for (int r = 0; r < 4; ++r) p[nj][r] = fast_exp2(s[nj][r] - m_);
    float rs = 0.f;
    #pragma unroll
    for (int nj = 0; nj < 4; ++nj)
      rs += (p[nj][0] + p[nj][1]) + (p[nj][2] + p[nj][3]);
    l_ += rs;            // per-lane partial; cross-quad reduce at epilogue
    #pragma unroll
    for (int nj = 0; nj < 4; ++nj) {
      uint2 u;
      u.x = cvt_pk_bf16(p[nj][0], p[nj][1]);
      u.y = cvt_pk_bf16(p[nj][2], p[nj][3]);
      *(uint2*)&psrow[nj * 16 + (quad << 2)] = u;
    }
  };

  auto compute_tile = [&]() {
    f32x4 s0[4], s1[4];
    #pragma unroll
    for (int nj = 0; nj < 4; ++nj) {
      s0[nj] = (f32x4){0.f, 0.f, 0.f, 0.f};
      s1[nj] = (f32x4){0.f, 0.f, 0.f, 0.f};
    }
    __builtin_amdgcn_s_setprio(1);
    #pragma unroll
    for (int ks = 0; ks < 2; ++ks) {
      #pragma unroll
      for (int nj = 0; nj < 4; ++nj) {
        bf16x8 aK = *(bf16x8*)&Ks[((nj << 4) + col) * GP + (ks << 5) + (quad << 3)];
        s0[nj] = __builtin_amdgcn_mfma_f32_16x16x32_bf16(aK, qf0[ks], s0[nj], 0, 0, 0);
        s1[nj] = __builtin_amdgcn_mfma_f32_16x16x32_bf16(aK, qf1[ks], s1[nj], 0, 0, 0);
      }
    }
    __builtin_amdgcn_s_setprio(0);
    softmax_strip(s0, m_0, l_0, o0, ps0);
    softmax_strip(s1, m_1, l_1, o1, ps1);
    __builtin_amdgcn_s_setprio(1);
    #pragma unroll
    for (int ks = 0; ks < 2; ++ks) {
      bf16x8 bP0 = *(bf16x8*)&ps0[(ks << 5) + (quad << 3)];
      bf16x8 bP1 = *(bf16x8*)&ps1[(ks << 5) + (quad << 3)];
      #pragma unroll
      for (int nd = 0; nd < 4; ++nd) {
        bf16x8 aV = *(bf16x8*)&VT[((nd << 4) + col) * GP + (ks << 5) + (quad << 3)];
        o0[nd] = __builtin_amdgcn_mfma_f32_16x16x32_bf16(aV, bP0, o0[nd], 0, 0, 0);
        o1[nd] = __builtin_amdgcn_mfma_f32_16x16x32_bf16(aV, bP1, o1[nd], 0, 0, 0);
      }
    }
    __builtin_amdgcn_s_setprio(0);
  };

  for (int kt = 0; kt < SEQ / 64 - 1; ++kt) {
    const short* kn = ksrc + (size_t)(kt + 1) * 64 * QKV_C;
    const short* vn = vsrc + (size_t)(kt + 1) * 64;
    bf16x8 ka = *(const bf16x8*)(kn);
    bf16x8 kb = *(const bf16x8*)(kn + 8);
    bf16x8 va = *(const bf16x8*)(vn);
    bf16x8 vb = *(const bf16x8*)(vn + 8);

    compute_tile();
    __syncthreads();                   // all waves done reading Ks/VT
    *(bf16x8*)&Ks[sr * GP + sc]     = ka;
    *(bf16x8*)&Ks[sr * GP + sc + 8] = kb;
    *(bf16x8*)&VT[sr * GP + sc]     = va;
    *(bf16x8*)&VT[sr * GP + sc + 8] = vb;
    __syncthreads();                   // next tile staged
  }
  compute_tile();                      // last tile

  // ---- epilogue: final cross-quad l reduce, O/l packed 8B stores ----
  float lt0 = l_0 + __shfl_xor(l_0, 16);
  lt0 += __shfl_xor(lt0, 32);
  float lt1 = l_1 + __shfl_xor(l_1, 16);
  lt1 += __shfl_xor(lt1, 32);
  #pragma unroll
  for (int s = 0; s < 2; ++s) {
    float inv = 1.f / (s ? lt1 : lt0);
    f32x4* o = s ? o1 : o0;
    size_t row = rowbase + qt * 128 + s * 64 + (w << 4) + col;
    #pragma unroll
    for (int nd = 0; nd < 4; ++nd) {
      uint2 u;
      u.x = cvt_pk_bf16(o[nd][0] * inv, o[nd][1] * inv);
      u.y = cvt_pk_bf16(o[nd][2] * inv, o[nd][3] * inv);
      *(uint2*)(qkvb + row * QKV_C + hoff + (nd << 4) + (quad << 2)) = u;
    }
  }
}

// ---------------- kernel 5: output projection, bf16 MFMA ----------------
// v10: depth-2 reg prefetch (same pattern as qkv_mfma_k).
__global__ __launch_bounds__(256) void proj_mfma_k(
    const short* __restrict__ Ab, const short* __restrict__ Wt,
    const float* __restrict__ bias, float* __restrict__ out) {
  __shared__ short As[128 * GP];
  __shared__ short Bs[128 * GP];
  int flat = blockIdx.y * 8 + blockIdx.x;
  int swz  = (flat & 7) * 64 + (flat >> 3);
  int n0 = (swz & 7) * 128, m0 = (swz >> 3) * 128;

  int tid  = threadIdx.x;
  int lane = tid & 63, w = tid >> 6;
  int wm = w >> 1, wn = w & 1;
  int col = lane & 15, quad = lane >> 4;
  int srow = tid >> 2;
  int scol = (tid & 3) << 4;

  const short* a0 = Ab + (size_t)(m0 + srow) * QKV_C + scol;
  const short* a1 = Ab + (size_t)(m0 + 64 + srow) * QKV_C + scol;
  const short* b0 = Wt + (size_t)(n0 + srow) * DP + scol;
  const short* b1 = Wt + (size_t)(n0 + 64 + srow) * DP + scol;

  f32x4 acc[4][4];
  #pragma unroll
  for (int mi = 0; mi < 4; ++mi)
    #pragma unroll
    for (int ni = 0; ni < 4; ++ni) acc[mi][ni] = (f32x4){0.f, 0.f, 0.f, 0.f};

  auto loadT = [&](bf16x8 (&r)[8], int k) {
    r[0] = *(const bf16x8*)(a0 + k);     r[1] = *(const bf16x8*)(a0 + k + 8);
    r[2] = *(const bf16x8*)(a1 + k);     r[3] = *(const bf16x8*)(a1 + k + 8);
    r[4] = *(const bf16x8*)(b0 + k);     r[5] = *(const bf16x8*)(b0 + k + 8);
    r[6] = *(const bf16x8*)(b1 + k);     r[7] = *(const bf16x8*)(b1 + k + 8);
  };
  auto stageT = [&](bf16x8 (&r)[8]) {
    *(bf16x8*)&As[srow * GP + scol]            = r[0];
    *(bf16x8*)&As[srow * GP + scol + 8]        = r[1];
    *(bf16x8*)&As[(64 + srow) * GP + scol]     = r[2];
    *(bf16x8*)&As[(64 + srow) * GP + scol + 8] = r[3];
    *(bf16x8*)&Bs[srow * GP + scol]            = r[4];
    *(bf16x8*)&Bs[srow * GP + scol + 8]        = r[5];
    *(bf16x8*)&Bs[(64 + srow) * GP + scol]     = r[6];
    *(bf16x8*)&Bs[(64 + srow) * GP + scol + 8] = r[7];
  };
  auto mfmaT = [&]() {
    #pragma unroll
    for (int ks = 0; ks < 2; ++ks) {
      bf16x8 a[4], b[4];
      #pragma unroll
      for (int mi = 0; mi < 4; ++mi)
        a[mi] = *(bf16x8*)&As[(wm * 64 + mi * 16 + col) * GP + ks * 32 + (quad << 3)];
      #pragma unroll
      for (int ni = 0; ni < 4; ++ni)
        b[ni] = *(bf16x8*)&Bs[(wn * 64 + ni * 16 + col) * GP + ks * 32 + (quad << 3)];
      #pragma unroll
      for (int mi = 0; mi < 4; ++mi)
        #pragma unroll
        for (int ni = 0; ni < 4; ++ni)
          acc[mi][ni] = __builtin_amdgcn_mfma_f32_16x16x32_bf16(a[mi], b[ni], acc[mi][ni], 0, 0, 0);
    }
  };

  bf16x8 rA[8], rB[8];
  loadT(rA, 0);
  loadT(rB, 64);
  for (int k0 = 0; k0 < DP; k0 += 128) {
    stageT(rA);
    __syncthreads();
    if (k0 + 128 < DP) loadT(rA, k0 + 128);
    mfmaT();
    __syncthreads();
    stageT(rB);
    __syncthreads();
    if (k0 + 192 < DP) loadT(rB, k0 + 192);
    mfmaT();
    __syncthreads();
  }

  #pragma unroll
  for (int mi = 0; mi < 4; ++mi) {
    #pragma unroll
    for (int r = 0; r < 4; ++r) {
      int m = m0 + wm * 64 + mi * 16 + (quad << 2) + r;
      #pragma unroll
      for (int ni = 0; ni < 4; ++ni) {
        int gn = n0 + wn * 64 + ni * 16 + col;
        out[(size_t)m * DM + gn] = acc[mi][ni][r] + bias[gn];
      }
    }
  }
}

// ---------------- launch ----------------
extern "C" void kernel_launch(void* const* d_in, const int* in_sizes, int n_in,
                              void* d_out, int out_size, void* d_ws, size_t ws_size,
                              hipStream_t stream) {
  (void)in_sizes; (void)n_in; (void)out_size; (void)ws_size;
  const float* X     = (const float*)d_in[0];
  const int*   L     = (const int*)d_in[1];
  const float* Wqkv  = (const float*)d_in[2];
  const float* bqkv  = (const float*)d_in[3];
  const float* Wproj = (const float*)d_in[4];
  const float* bproj = (const float*)d_in[5];
  float* out = (float*)d_out;

  char* ws = (char*)d_ws;
  short* qkvb    = (short*)ws;                                   // 8192x3072 bf16 (50.3 MB)
  short* Wqkv_t  = (short*)(ws + (size_t)TOK * QKV_C * 2);       // 8x3072x1024 bf16 (50.3 MB)
  short* Wproj_t = (short*)(ws + (size_t)TOK * QKV_C * 2
                               + (size_t)NLAB * QKV_C * DM * 2); // 1024x1024 bf16 (2.1 MB)
  int* sorted = (int*)((char*)Wproj_t + (size_t)DP * DM * 2);
  int* rowmap = sorted + TOK;
  short* Xg = (short*)(rowmap + PROWS);                          // 9216x1024 bf16 (18.9 MB)
  // VT[b][h][d][n] bf16 (16.8 MB) aliases Wqkv_t, which is dead after
  // qkv_mfma_k and re-built by wt_k at the start of each iteration.
  short* VTg = Wqkv_t;

  build_lists_k<<<dim3(1), dim3(256), 0, stream>>>(L, sorted, rowmap);
  xg_k<<<dim3(PROWS), dim3(256), 0, stream>>>(X, rowmap, Xg);
  wt_k<<<dim3(QKV_C / 64, DM / 64, NLAB), dim3(256), 0, stream>>>(Wqkv, Wqkv_t, DM, QKV_C);
  wt_k<<<dim3(DM / 64, DP / 64, 1), dim3(256), 0, stream>>>(Wproj, Wproj_t, DP, DM);
  qkv_mfma_k<<<dim3(QKV_C / 128, PROWS / 128), dim3(256), 0, stream>>>(
      Xg, Wqkv_t, bqkv, rowmap, qkvb);
  vtb_k<<<dim3(SEQ / 64, NH, BATCH), dim3(256), 0, stream>>>(qkvb, VTg);
  attn_k<<<dim3(SEQ / 128, NH, BATCH), dim3(256), 0, stream>>>(qkvb, VTg);
  proj_mfma_k<<<dim3(DM / 128, TOK / 128), dim3(256), 0, stream>>>(
      qkvb, Wproj_t, bproj, out);
}

// Round 14
// 457.724 us; speedup vs baseline: 1.0768x; 1.0242x over previous
//
#include <hip/hip_runtime.h>
#include <math.h>

#define BATCH 4
#define SEQ   2048
#define TOK   (BATCH * SEQ)   // 8192
#define DM    1024
#define DP    1024
#define NH    16
#define DH    64
#define NLAB  8
#define QKV_C 3072
#define PADL  1152            // padded rows per label (9 x 128)
#define PROWS (NLAB * PADL)   // 9216
#define GP    72              // LDS row pitch (bf16 elems) - verified conflict-free

typedef __attribute__((ext_vector_type(8))) short bf16x8;
typedef __attribute__((ext_vector_type(4))) float f32x4;

__device__ __forceinline__ short f2bf(float f) {
  union { float f; unsigned u; } v; v.f = f;
  unsigned r = v.u + 0x7FFF + ((v.u >> 16) & 1);   // RNE
  return (short)(r >> 16);
}

__device__ __forceinline__ unsigned cvt_pk_bf16(float lo, float hi) {
  unsigned r;
  asm("v_cvt_pk_bf16_f32 %0, %1, %2" : "=v"(r) : "v"(lo), "v"(hi));
  return r;
}

__device__ __forceinline__ float fast_exp2(float x) {
#if __has_builtin(__builtin_amdgcn_exp2f)
  return __builtin_amdgcn_exp2f(x);
#else
  return exp2f(x);
#endif
}

__device__ __forceinline__ float max3f(float a, float b, float c) {
  return fmaxf(fmaxf(a, b), c);   // clang fuses to v_max3_f32
}

// ---------------- kernel 1: bucket tokens, build padded rowmap ----------------
__global__ void build_lists_k(const int* __restrict__ L, int* __restrict__ sorted,
                              int* __restrict__ rowmap) {
  __shared__ int cnt[NLAB], off[NLAB], cur[NLAB];
  int tid = threadIdx.x;
  if (tid < NLAB) cnt[tid] = 0;
  __syncthreads();
  for (int i = tid; i < TOK; i += 256) atomicAdd(&cnt[L[i]], 1);
  __syncthreads();
  if (tid == 0) {
    int o = 0;
    for (int l = 0; l < NLAB; ++l) { off[l] = o; cur[l] = o; o += cnt[l]; }
  }
  __syncthreads();
  for (int i = tid; i < TOK; i += 256) {
    int l = L[i];
    sorted[atomicAdd(&cur[l], 1)] = i;
  }
  __threadfence();
  __syncthreads();
  for (int p = tid; p < PROWS; p += 256) {
    int l = p / PADL, i = p - l * PADL;
    rowmap[p] = (i < cnt[l]) ? sorted[off[l] + i] : -1;
  }
}

// ---------------- kernel 2: fused prep - X gather/convert + both W transposes
__global__ __launch_bounds__(256) void prep_k(
    const float* __restrict__ X, const int* __restrict__ rowmap,
    short* __restrict__ Xg,
    const float* __restrict__ Wqkv, short* __restrict__ Wqkv_t,
    const float* __restrict__ Wproj, short* __restrict__ Wproj_t) {
  __shared__ float Ts[64][65];
  int bid = blockIdx.x;
  int tid = threadIdx.x;
  if (bid < PROWS) {
    int t = rowmap[bid];
    int c = tid << 2;
    short* dst = Xg + (size_t)bid * DM + c;
    if (t >= 0) {
      float4 v = *(const float4*)(X + (size_t)t * DM + c);
      short tmp[4] = { f2bf(v.x), f2bf(v.y), f2bf(v.z), f2bf(v.w) };
      *(uint2*)dst = *(uint2*)tmp;
    } else {
      uint2 z; z.x = 0u; z.y = 0u;
      *(uint2*)dst = z;
    }
    return;
  }
  const float* src; short* dst; int K, N, n0, k0;
  int b2 = bid - PROWS;
  if (b2 < 6144) {                       // Wqkv: 8 mats x (16 k-tiles x 48 n-tiles)
    int m = b2 / 768, rem = b2 % 768;
    K = DM; N = QKV_C;
    src = Wqkv + (size_t)m * K * N;
    dst = Wqkv_t + (size_t)m * (size_t)N * K;
    k0 = (rem / 48) * 64; n0 = (rem % 48) * 64;
  } else {                               // Wproj: 16 x 16 tiles
    int b3 = b2 - 6144;
    K = DP; N = DM;
    src = Wproj; dst = Wproj_t;
    k0 = (b3 / 16) * 64; n0 = (b3 % 16) * 64;
  }
  int r = tid >> 4;
  int c = (tid & 15) << 2;
  #pragma unroll
  for (int it = 0; it < 4; ++it) {
    float4 v = *(const float4*)(src + (size_t)(k0 + r + it * 16) * N + n0 + c);
    Ts[c + 0][r + it * 16] = v.x;
    Ts[c + 1][r + it * 16] = v.y;
    Ts[c + 2][r + it * 16] = v.z;
    Ts[c + 3][r + it * 16] = v.w;
  }
  __syncthreads();
  int n = tid >> 2, ks = (tid & 3) << 4;
  short tmp[16];
  #pragma unroll
  for (int j = 0; j < 16; ++j) tmp[j] = f2bf(Ts[n][ks + j]);
  *(bf16x8*)(dst + (size_t)(n0 + n) * K + k0 + ks)     = *(bf16x8*)&tmp[0];
  *(bf16x8*)(dst + (size_t)(n0 + n) * K + k0 + ks + 8) = *(bf16x8*)&tmp[8];
}

// ---------------- kernel 3: label-routed QKV GEMM, bf16 MFMA ----------------
// v8 structure (best of 4 staging variants): depth-1 reg prefetch, GP=72 LDS.
__global__ __launch_bounds__(256) void qkv_mfma_k(
    const short* __restrict__ Xg, const short* __restrict__ Wt,
    const float* __restrict__ bqkv, const int* __restrict__ rowmap,
    short* __restrict__ qkvb) {
  __shared__ short As[128 * GP];
  __shared__ short Bs[128 * GP];
  int flat = blockIdx.y * 24 + blockIdx.x;
  int swz  = (flat & 7) * 216 + (flat >> 3);
  int bx = swz % 24, by = swz / 24;
  int lab = by / 9;
  int pr0 = by * 128;
  int n0  = bx * 128;
  const short* W = Wt + (size_t)lab * QKV_C * DM;   // [3072][1024] bf16

  int tid  = threadIdx.x;
  int lane = tid & 63, w = tid >> 6;
  int wm = w >> 1, wn = w & 1;
  int col = lane & 15, quad = lane >> 4;

  int srow = tid >> 2;            // staging row 0..63 (+64 on 2nd rep)
  int scol = (tid & 3) << 4;      // staging col 0,16,32,48

  const short* a0 = Xg + (size_t)(pr0 + srow) * DM + scol;
  const short* a1 = Xg + (size_t)(pr0 + 64 + srow) * DM + scol;
  const short* b0 = W + (size_t)(n0 + srow) * DM + scol;
  const short* b1 = W + (size_t)(n0 + 64 + srow) * DM + scol;

  f32x4 acc[4][4];
  #pragma unroll
  for (int mi = 0; mi < 4; ++mi)
    #pragma unroll
    for (int ni = 0; ni < 4; ++ni) acc[mi][ni] = (f32x4){0.f, 0.f, 0.f, 0.f};

  bf16x8 ra[4], rb[4];
  ra[0] = *(const bf16x8*)(a0);     ra[1] = *(const bf16x8*)(a0 + 8);
  ra[2] = *(const bf16x8*)(a1);     ra[3] = *(const bf16x8*)(a1 + 8);
  rb[0] = *(const bf16x8*)(b0);     rb[1] = *(const bf16x8*)(b0 + 8);
  rb[2] = *(const bf16x8*)(b1);     rb[3] = *(const bf16x8*)(b1 + 8);

  for (int k0 = 0; k0 < DM; k0 += 64) {
    *(bf16x8*)&As[srow * GP + scol]            = ra[0];
    *(bf16x8*)&As[srow * GP + scol + 8]        = ra[1];
    *(bf16x8*)&As[(64 + srow) * GP + scol]     = ra[2];
    *(bf16x8*)&As[(64 + srow) * GP + scol + 8] = ra[3];
    *(bf16x8*)&Bs[srow * GP + scol]            = rb[0];
    *(bf16x8*)&Bs[srow * GP + scol + 8]        = rb[1];
    *(bf16x8*)&Bs[(64 + srow) * GP + scol]     = rb[2];
    *(bf16x8*)&Bs[(64 + srow) * GP + scol + 8] = rb[3];
    __syncthreads();
    if (k0 + 64 < DM) {
      int kn = k0 + 64;
      ra[0] = *(const bf16x8*)(a0 + kn);     ra[1] = *(const bf16x8*)(a0 + kn + 8);
      ra[2] = *(const bf16x8*)(a1 + kn);     ra[3] = *(const bf16x8*)(a1 + kn + 8);
      rb[0] = *(const bf16x8*)(b0 + kn);     rb[1] = *(const bf16x8*)(b0 + kn + 8);
      rb[2] = *(const bf16x8*)(b1 + kn);     rb[3] = *(const bf16x8*)(b1 + kn + 8);
    }
    #pragma unroll
    for (int ks = 0; ks < 2; ++ks) {
      bf16x8 a[4], b[4];
      #pragma unroll
      for (int mi = 0; mi < 4; ++mi)
        a[mi] = *(bf16x8*)&As[(wm * 64 + mi * 16 + col) * GP + ks * 32 + (quad << 3)];
      #pragma unroll
      for (int ni = 0; ni < 4; ++ni)
        b[ni] = *(bf16x8*)&Bs[(wn * 64 + ni * 16 + col) * GP + ks * 32 + (quad << 3)];
      #pragma unroll
      for (int mi = 0; mi < 4; ++mi)
        #pragma unroll
        for (int ni = 0; ni < 4; ++ni)
          acc[mi][ni] = __builtin_amdgcn_mfma_f32_16x16x32_bf16(a[mi], b[ni], acc[mi][ni], 0, 0, 0);
    }
    __syncthreads();
  }

  float scale = (bx < 8) ? (0.125f * 1.44269504f) : 1.0f;
  const float* bias = bqkv + lab * QKV_C;
  #pragma unroll
  for (int mi = 0; mi < 4; ++mi) {
    #pragma unroll
    for (int r = 0; r < 4; ++r) {
      int prow = pr0 + wm * 64 + mi * 16 + (quad << 2) + r;
      int t2 = rowmap[prow];
      if (t2 < 0) continue;
      #pragma unroll
      for (int ni = 0; ni < 4; ++ni) {
        int gn = n0 + wn * 64 + ni * 16 + col;
        float v = (acc[mi][ni][r] + bias[gn]) * scale;
        qkvb[(size_t)t2 * QKV_C + gn] = f2bf(v);
      }
    }
  }
}

// ---------------- kernel 3b: V transpose  qkvb V-region -> VT[b][h][d][n] ----
__global__ __launch_bounds__(256) void vtb_k(const short* __restrict__ qkvb,
                                             short* __restrict__ VTg) {
  __shared__ short T[64 * GP];
  int n0 = blockIdx.x * 64, h = blockIdx.y, b = blockIdx.z;
  int tid = threadIdx.x;
  int r = tid >> 2, cb = tid & 3;
  {
    const short* src = qkvb + ((size_t)(b * SEQ + n0 + r)) * QKV_C + 2 * DP + h * DH + (cb << 4);
    int scc = ((cb + (r >> 4)) & 3) << 4;   // rotated chunk
    *(bf16x8*)&T[r * GP + scc]     = *(const bf16x8*)(src);
    *(bf16x8*)&T[r * GP + scc + 8] = *(const bf16x8*)(src + 8);
  }
  __syncthreads();
  int d = tid >> 2, nc = (tid & 3) << 4;
  int sc2 = (((d >> 4) + (nc >> 4)) & 3) << 4;
  short tmp[16];
  #pragma unroll
  for (int j = 0; j < 16; ++j) tmp[j] = T[(nc + j) * GP + sc2 + (d & 15)];
  short* dst = VTg + ((size_t)(b * NH + h) * DH + d) * SEQ + n0 + nc;
  *(bf16x8*)&dst[0] = *(bf16x8*)&tmp[0];
  *(bf16x8*)&dst[8] = *(bf16x8*)&tmp[8];
}

// ---------------- kernel 4: flash attention, bf16 MFMA, bf16 I/O -----------
// v12: VERIFIED v8/v10 softmax restored (per-lane partial l + epilogue shfl
// reduce; ones-MFMA l from v11 reverted pending bisect) + max3 tree (safe).
__global__ __launch_bounds__(256) void attn_k(short* __restrict__ qkvb,
                                              const short* __restrict__ VTg) {
  int qt = blockIdx.x, h = blockIdx.y, b = blockIdx.z;
  __shared__ short Ks[64 * GP];
  __shared__ short VT[64 * GP];    // VT[d][kv]
  __shared__ short Ps[128 * GP];   // [q 0..127][kv 0..63]

  int tid  = threadIdx.x;
  int lane = tid & 63;
  int w    = tid >> 6;
  int col  = lane & 15;
  int quad = lane >> 4;

  size_t rowbase = (size_t)b * SEQ;
  int hoff = h * DH;
  int sr = tid >> 2;            // staging row 0..63
  int sc = (tid & 3) << 4;      // staging col 0,16,32,48

  const short* ksrc = qkvb + (rowbase + sr) * QKV_C + DP + hoff + sc;
  const short* vsrc = VTg + ((size_t)(b * NH + h) * DH + sr) * SEQ + sc;

  // ---- Q B-fragments: direct global load, loop-invariant (2 strips) ----
  bf16x8 qf0[2], qf1[2];
  {
    const short* q0 = qkvb + (rowbase + qt * 128 + (w << 4) + col) * QKV_C + hoff + (quad << 3);
    const short* q1 = q0 + (size_t)64 * QKV_C;
    qf0[0] = *(const bf16x8*)(q0);
    qf0[1] = *(const bf16x8*)(q0 + 32);
    qf1[0] = *(const bf16x8*)(q1);
    qf1[1] = *(const bf16x8*)(q1 + 32);
  }

  // ---- preload kv tile 0 ----
  {
    bf16x8 ka = *(const bf16x8*)(ksrc);
    bf16x8 kb = *(const bf16x8*)(ksrc + 8);
    bf16x8 va = *(const bf16x8*)(vsrc);
    bf16x8 vb = *(const bf16x8*)(vsrc + 8);
    *(bf16x8*)&Ks[sr * GP + sc]     = ka;
    *(bf16x8*)&Ks[sr * GP + sc + 8] = kb;
    *(bf16x8*)&VT[sr * GP + sc]     = va;
    *(bf16x8*)&VT[sr * GP + sc + 8] = vb;
  }
  __syncthreads();

  float m_0 = -1e30f, l_0 = 0.f, m_1 = -1e30f, l_1 = 0.f;
  f32x4 o0[4], o1[4];   // O^T: lane holds O[q=col][d = nd*16 + quad*4 + r]
  #pragma unroll
  for (int nd = 0; nd < 4; ++nd) {
    o0[nd] = (f32x4){0.f, 0.f, 0.f, 0.f};
    o1[nd] = (f32x4){0.f, 0.f, 0.f, 0.f};
  }

  short* ps0 = &Ps[((w << 4) + col) * GP];
  short* ps1 = &Ps[(64 + (w << 4) + col) * GP];

  auto softmax_strip = [&](f32x4* s, float& m_, float& l_, f32x4* o, short* psrow) {
    // 3-ary max tree over this lane's 16 kv values (v_max3)
    float g0 = max3f(s[0][0], s[0][1], s[0][2]);
    float g1 = max3f(s[0][3], s[1][0], s[1][1]);
    float g2 = max3f(s[1][2], s[1][3], s[2][0]);
    float g3 = max3f(s[2][1], s[2][2], s[2][3]);
    float g4 = max3f(s[3][0], s[3][1], s[3][2]);
    float mx = fmaxf(max3f(g0, g1, g2), max3f(g3, g4, s[3][3]));
    if (!__all(mx - m_ <= 8.f)) {
      float mxr = fmaxf(mx, __shfl_xor(mx, 16));
      mxr = fmaxf(mxr, __shfl_xor(mxr, 32));
      float mnew  = fmaxf(m_, mxr);
      float alpha = fast_exp2(m_ - mnew);
      l_ *= alpha;
      #pragma unroll
      for (int nd = 0; nd < 4; ++nd)
        #pragma unroll
        for (int r = 0; r < 4; ++r) o[nd][r] *= alpha;
      m_ = mnew;
    }
    float p[4][4];
    #pragma unroll
    for (int nj = 0; nj < 4; ++nj)
      #pragma unroll
      for (int r = 0; r < 4; ++r) p[nj][r] = fast_exp2(s[nj][r] - m_);
    float rs = 0.f;
    #pragma unroll
    for (int nj = 0; nj < 4; ++nj)
      rs += (p[nj][0] + p[nj][1]) + (p[nj][2] + p[nj][3]);
    l_ += rs;            // per-lane partial; cross-quad reduce at epilogue
    #pragma unroll
    for (int nj = 0; nj < 4; ++nj) {
      uint2 u;
      u.x = cvt_pk_bf16(p[nj][0], p[nj][1]);
      u.y = cvt_pk_bf16(p[nj][2], p[nj][3]);
      *(uint2*)&psrow[nj * 16 + (quad << 2)] = u;
    }
  };

  auto compute_tile = [&]() {
    f32x4 s0[4], s1[4];
    #pragma unroll
    for (int nj = 0; nj < 4; ++nj) {
      s0[nj] = (f32x4){0.f, 0.f, 0.f, 0.f};
      s1[nj] = (f32x4){0.f, 0.f, 0.f, 0.f};
    }
    __builtin_amdgcn_s_setprio(1);
    #pragma unroll
    for (int ks = 0; ks < 2; ++ks) {
      #pragma unroll
      for (int nj = 0; nj < 4; ++nj) {
        bf16x8 aK = *(bf16x8*)&Ks[((nj << 4) + col) * GP + (ks << 5) + (quad << 3)];
        s0[nj] = __builtin_amdgcn_mfma_f32_16x16x32_bf16(aK, qf0[ks], s0[nj], 0, 0, 0);
        s1[nj] = __builtin_amdgcn_mfma_f32_16x16x32_bf16(aK, qf1[ks], s1[nj], 0, 0, 0);
      }
    }
    __builtin_amdgcn_s_setprio(0);
    softmax_strip(s0, m_0, l_0, o0, ps0);
    softmax_strip(s1, m_1, l_1, o1, ps1);
    __builtin_amdgcn_s_setprio(1);
    #pragma unroll
    for (int ks = 0; ks < 2; ++ks) {
      bf16x8 bP0 = *(bf16x8*)&ps0[(ks << 5) + (quad << 3)];
      bf16x8 bP1 = *(bf16x8*)&ps1[(ks << 5) + (quad << 3)];
      #pragma unroll
      for (int nd = 0; nd < 4; ++nd) {
        bf16x8 aV = *(bf16x8*)&VT[((nd << 4) + col) * GP + (ks << 5) + (quad << 3)];
        o0[nd] = __builtin_amdgcn_mfma_f32_16x16x32_bf16(aV, bP0, o0[nd], 0, 0, 0);
        o1[nd] = __builtin_amdgcn_mfma_f32_16x16x32_bf16(aV, bP1, o1[nd], 0, 0, 0);
      }
    }
    __builtin_amdgcn_s_setprio(0);
  };

  for (int kt = 0; kt < SEQ / 64 - 1; ++kt) {
    const short* kn = ksrc + (size_t)(kt + 1) * 64 * QKV_C;
    const short* vn = vsrc + (size_t)(kt + 1) * 64;
    bf16x8 ka = *(const bf16x8*)(kn);
    bf16x8 kb = *(const bf16x8*)(kn + 8);
    bf16x8 va = *(const bf16x8*)(vn);
    bf16x8 vb = *(const bf16x8*)(vn + 8);

    compute_tile();
    __syncthreads();                   // all waves done reading Ks/VT
    *(bf16x8*)&Ks[sr * GP + sc]     = ka;
    *(bf16x8*)&Ks[sr * GP + sc + 8] = kb;
    *(bf16x8*)&VT[sr * GP + sc]     = va;
    *(bf16x8*)&VT[sr * GP + sc + 8] = vb;
    __syncthreads();                   // next tile staged
  }
  compute_tile();                      // last tile

  // ---- epilogue: final cross-quad l reduce, O/l packed 8B stores ----
  float lt0 = l_0 + __shfl_xor(l_0, 16);
  lt0 += __shfl_xor(lt0, 32);
  float lt1 = l_1 + __shfl_xor(l_1, 16);
  lt1 += __shfl_xor(lt1, 32);
  #pragma unroll
  for (int s = 0; s < 2; ++s) {
    float inv = 1.f / (s ? lt1 : lt0);
    f32x4* o = s ? o1 : o0;
    size_t row = rowbase + qt * 128 + s * 64 + (w << 4) + col;
    #pragma unroll
    for (int nd = 0; nd < 4; ++nd) {
      uint2 u;
      u.x = cvt_pk_bf16(o[nd][0] * inv, o[nd][1] * inv);
      u.y = cvt_pk_bf16(o[nd][2] * inv, o[nd][3] * inv);
      *(uint2*)(qkvb + row * QKV_C + hoff + (nd << 4) + (quad << 2)) = u;
    }
  }
}

// ---------------- kernel 5: output projection, bf16 MFMA ----------------
__global__ __launch_bounds__(256) void proj_mfma_k(
    const short* __restrict__ Ab, const short* __restrict__ Wt,
    const float* __restrict__ bias, float* __restrict__ out) {
  __shared__ short As[128 * GP];
  __shared__ short Bs[128 * GP];
  int flat = blockIdx.y * 8 + blockIdx.x;
  int swz  = (flat & 7) * 64 + (flat >> 3);
  int n0 = (swz & 7) * 128, m0 = (swz >> 3) * 128;

  int tid  = threadIdx.x;
  int lane = tid & 63, w = tid >> 6;
  int wm = w >> 1, wn = w & 1;
  int col = lane & 15, quad = lane >> 4;
  int srow = tid >> 2;
  int scol = (tid & 3) << 4;

  const short* a0 = Ab + (size_t)(m0 + srow) * QKV_C + scol;
  const short* a1 = Ab + (size_t)(m0 + 64 + srow) * QKV_C + scol;
  const short* b0 = Wt + (size_t)(n0 + srow) * DP + scol;
  const short* b1 = Wt + (size_t)(n0 + 64 + srow) * DP + scol;

  f32x4 acc[4][4];
  #pragma unroll
  for (int mi = 0; mi < 4; ++mi)
    #pragma unroll
    for (int ni = 0; ni < 4; ++ni) acc[mi][ni] = (f32x4){0.f, 0.f, 0.f, 0.f};

  bf16x8 ra[4], rb[4];
  ra[0] = *(const bf16x8*)(a0);     ra[1] = *(const bf16x8*)(a0 + 8);
  ra[2] = *(const bf16x8*)(a1);     ra[3] = *(const bf16x8*)(a1 + 8);
  rb[0] = *(const bf16x8*)(b0);     rb[1] = *(const bf16x8*)(b0 + 8);
  rb[2] = *(const bf16x8*)(b1);     rb[3] = *(const bf16x8*)(b1 + 8);

  for (int k0 = 0; k0 < DP; k0 += 64) {
    *(bf16x8*)&As[srow * GP + scol]            = ra[0];
    *(bf16x8*)&As[srow * GP + scol + 8]        = ra[1];
    *(bf16x8*)&As[(64 + srow) * GP + scol]     = ra[2];
    *(bf16x8*)&As[(64 + srow) * GP + scol + 8] = ra[3];
    *(bf16x8*)&Bs[srow * GP + scol]            = rb[0];
    *(bf16x8*)&Bs[srow * GP + scol + 8]        = rb[1];
    *(bf16x8*)&Bs[(64 + srow) * GP + scol]     = rb[2];
    *(bf16x8*)&Bs[(64 + srow) * GP + scol + 8] = rb[3];
    __syncthreads();
    if (k0 + 64 < DP) {
      int kn = k0 + 64;
      ra[0] = *(const bf16x8*)(a0 + kn);     ra[1] = *(const bf16x8*)(a0 + kn + 8);
      ra[2] = *(const bf16x8*)(a1 + kn);     ra[3] = *(const bf16x8*)(a1 + kn + 8);
      rb[0] = *(const bf16x8*)(b0 + kn);     rb[1] = *(const bf16x8*)(b0 + kn + 8);
      rb[2] = *(const bf16x8*)(b1 + kn);     rb[3] = *(const bf16x8*)(b1 + kn + 8);
    }
    #pragma unroll
    for (int ks = 0; ks < 2; ++ks) {
      bf16x8 a[4], b[4];
      #pragma unroll
      for (int mi = 0; mi < 4; ++mi)
        a[mi] = *(bf16x8*)&As[(wm * 64 + mi * 16 + col) * GP + ks * 32 + (quad << 3)];
      #pragma unroll
      for (int ni = 0; ni < 4; ++ni)
        b[ni] = *(bf16x8*)&Bs[(wn * 64 + ni * 16 + col) * GP + ks * 32 + (quad << 3)];
      #pragma unroll
      for (int mi = 0; mi < 4; ++mi)
        #pragma unroll
        for (int ni = 0; ni < 4; ++ni)
          acc[mi][ni] = __builtin_amdgcn_mfma_f32_16x16x32_bf16(a[mi], b[ni], acc[mi][ni], 0, 0, 0);
    }
    __syncthreads();
  }

  #pragma unroll
  for (int mi = 0; mi < 4; ++mi) {
    #pragma unroll
    for (int r = 0; r < 4; ++r) {
      int m = m0 + wm * 64 + mi * 16 + (quad << 2) + r;
      #pragma unroll
      for (int ni = 0; ni < 4; ++ni) {
        int gn = n0 + wn * 64 + ni * 16 + col;
        out[(size_t)m * DM + gn] = acc[mi][ni][r] + bias[gn];
      }
    }
  }
}

// ---------------- launch ----------------
extern "C" void kernel_launch(void* const* d_in, const int* in_sizes, int n_in,
                              void* d_out, int out_size, void* d_ws, size_t ws_size,
                              hipStream_t stream) {
  (void)in_sizes; (void)n_in; (void)out_size; (void)ws_size;
  const float* X     = (const float*)d_in[0];
  const int*   L     = (const int*)d_in[1];
  const float* Wqkv  = (const float*)d_in[2];
  const float* bqkv  = (const float*)d_in[3];
  const float* Wproj = (const float*)d_in[4];
  const float* bproj = (const float*)d_in[5];
  float* out = (float*)d_out;

  char* ws = (char*)d_ws;
  short* qkvb    = (short*)ws;                                   // 8192x3072 bf16 (50.3 MB)
  short* Wqkv_t  = (short*)(ws + (size_t)TOK * QKV_C * 2);       // 8x3072x1024 bf16 (50.3 MB)
  short* Wproj_t = (short*)(ws + (size_t)TOK * QKV_C * 2
                               + (size_t)NLAB * QKV_C * DM * 2); // 1024x1024 bf16 (2.1 MB)
  int* sorted = (int*)((char*)Wproj_t + (size_t)DP * DM * 2);
  int* rowmap = sorted + TOK;
  short* Xg = (short*)(rowmap + PROWS);                          // 9216x1024 bf16 (18.9 MB)
  // VT[b][h][d][n] bf16 (16.8 MB) aliases Wqkv_t, which is dead after
  // qkv_mfma_k and re-built by prep_k at the start of each iteration.
  short* VTg = Wqkv_t;

  build_lists_k<<<dim3(1), dim3(256), 0, stream>>>(L, sorted, rowmap);
  prep_k<<<dim3(PROWS + 6144 + 256), dim3(256), 0, stream>>>(
      X, rowmap, Xg, Wqkv, Wqkv_t, Wproj, Wproj_t);
  qkv_mfma_k<<<dim3(QKV_C / 128, PROWS / 128), dim3(256), 0, stream>>>(
      Xg, Wqkv_t, bqkv, rowmap, qkvb);
  vtb_k<<<dim3(SEQ / 64, NH, BATCH), dim3(256), 0, stream>>>(qkvb, VTg);
  attn_k<<<dim3(SEQ / 128, NH, BATCH), dim3(256), 0, stream>>>(qkvb, VTg);
  proj_mfma_k<<<dim3(DM / 128, TOK / 128), dim3(256), 0, stream>>>(
      qkvb, Wproj_t, bproj, out);
}

// Round 15
// 435.154 us; speedup vs baseline: 1.1326x; 1.0519x over previous
//
#include <hip/hip_runtime.h>
#include <math.h>

#define BATCH 4
#define SEQ   2048
#define TOK   (BATCH * SEQ)   // 8192
#define DM    1024
#define DP    1024
#define NH    16
#define DH    64
#define NLAB  8
#define QKV_C 3072
#define PADL  1152            // padded rows per label (9 x 128)
#define PROWS (NLAB * PADL)   // 9216
#define GP    72              // LDS row pitch (bf16 elems) - verified conflict-free

typedef __attribute__((ext_vector_type(8))) short bf16x8;
typedef __attribute__((ext_vector_type(4))) float f32x4;

__device__ __forceinline__ short f2bf(float f) {
  union { float f; unsigned u; } v; v.f = f;
  unsigned r = v.u + 0x7FFF + ((v.u >> 16) & 1);   // RNE
  return (short)(r >> 16);
}

__device__ __forceinline__ unsigned cvt_pk_bf16(float lo, float hi) {
  unsigned r;
  asm("v_cvt_pk_bf16_f32 %0, %1, %2" : "=v"(r) : "v"(lo), "v"(hi));
  return r;
}

__device__ __forceinline__ float fast_exp2(float x) {
#if __has_builtin(__builtin_amdgcn_exp2f)
  return __builtin_amdgcn_exp2f(x);
#else
  return exp2f(x);
#endif
}

__device__ __forceinline__ float max3f(float a, float b, float c) {
  return fmaxf(fmaxf(a, b), c);   // clang fuses to v_max3_f32
}

// ---------------- kernel 1: bucket tokens, build padded rowmap ----------------
__global__ void build_lists_k(const int* __restrict__ L, int* __restrict__ sorted,
                              int* __restrict__ rowmap) {
  __shared__ int cnt[NLAB], off[NLAB], cur[NLAB];
  int tid = threadIdx.x;
  if (tid < NLAB) cnt[tid] = 0;
  __syncthreads();
  for (int i = tid; i < TOK; i += 256) atomicAdd(&cnt[L[i]], 1);
  __syncthreads();
  if (tid == 0) {
    int o = 0;
    for (int l = 0; l < NLAB; ++l) { off[l] = o; cur[l] = o; o += cnt[l]; }
  }
  __syncthreads();
  for (int i = tid; i < TOK; i += 256) {
    int l = L[i];
    sorted[atomicAdd(&cur[l], 1)] = i;
  }
  __threadfence();
  __syncthreads();
  for (int p = tid; p < PROWS; p += 256) {
    int l = p / PADL, i = p - l * PADL;
    rowmap[p] = (i < cnt[l]) ? sorted[off[l] + i] : -1;
  }
}

// ---------------- kernel 2: fused prep - X gather/convert + both W transposes
__global__ __launch_bounds__(256) void prep_k(
    const float* __restrict__ X, const int* __restrict__ rowmap,
    short* __restrict__ Xg,
    const float* __restrict__ Wqkv, short* __restrict__ Wqkv_t,
    const float* __restrict__ Wproj, short* __restrict__ Wproj_t) {
  __shared__ float Ts[64][65];
  int bid = blockIdx.x;
  int tid = threadIdx.x;
  if (bid < PROWS) {
    int t = rowmap[bid];
    int c = tid << 2;
    short* dst = Xg + (size_t)bid * DM + c;
    if (t >= 0) {
      float4 v = *(const float4*)(X + (size_t)t * DM + c);
      short tmp[4] = { f2bf(v.x), f2bf(v.y), f2bf(v.z), f2bf(v.w) };
      *(uint2*)dst = *(uint2*)tmp;
    } else {
      uint2 z; z.x = 0u; z.y = 0u;
      *(uint2*)dst = z;
    }
    return;
  }
  const float* src; short* dst; int K, N, n0, k0;
  int b2 = bid - PROWS;
  if (b2 < 6144) {                       // Wqkv: 8 mats x (16 k-tiles x 48 n-tiles)
    int m = b2 / 768, rem = b2 % 768;
    K = DM; N = QKV_C;
    src = Wqkv + (size_t)m * K * N;
    dst = Wqkv_t + (size_t)m * (size_t)N * K;
    k0 = (rem / 48) * 64; n0 = (rem % 48) * 64;
  } else {                               // Wproj: 16 x 16 tiles
    int b3 = b2 - 6144;
    K = DP; N = DM;
    src = Wproj; dst = Wproj_t;
    k0 = (b3 / 16) * 64; n0 = (b3 % 16) * 64;
  }
  int r = tid >> 4;
  int c = (tid & 15) << 2;
  #pragma unroll
  for (int it = 0; it < 4; ++it) {
    float4 v = *(const float4*)(src + (size_t)(k0 + r + it * 16) * N + n0 + c);
    Ts[c + 0][r + it * 16] = v.x;
    Ts[c + 1][r + it * 16] = v.y;
    Ts[c + 2][r + it * 16] = v.z;
    Ts[c + 3][r + it * 16] = v.w;
  }
  __syncthreads();
  int n = tid >> 2, ks = (tid & 3) << 4;
  short tmp[16];
  #pragma unroll
  for (int j = 0; j < 16; ++j) tmp[j] = f2bf(Ts[n][ks + j]);
  *(bf16x8*)(dst + (size_t)(n0 + n) * K + k0 + ks)     = *(bf16x8*)&tmp[0];
  *(bf16x8*)(dst + (size_t)(n0 + n) * K + k0 + ks + 8) = *(bf16x8*)&tmp[8];
}

// ---------------- kernel 3: label-routed QKV GEMM, bf16 MFMA ----------------
// v8 structure (best of 4 staging variants): depth-1 reg prefetch, GP=72 LDS.
__global__ __launch_bounds__(256) void qkv_mfma_k(
    const short* __restrict__ Xg, const short* __restrict__ Wt,
    const float* __restrict__ bqkv, const int* __restrict__ rowmap,
    short* __restrict__ qkvb) {
  __shared__ short As[128 * GP];
  __shared__ short Bs[128 * GP];
  int flat = blockIdx.y * 24 + blockIdx.x;
  int swz  = (flat & 7) * 216 + (flat >> 3);
  int bx = swz % 24, by = swz / 24;
  int lab = by / 9;
  int pr0 = by * 128;
  int n0  = bx * 128;
  const short* W = Wt + (size_t)lab * QKV_C * DM;   // [3072][1024] bf16

  int tid  = threadIdx.x;
  int lane = tid & 63, w = tid >> 6;
  int wm = w >> 1, wn = w & 1;
  int col = lane & 15, quad = lane >> 4;

  int srow = tid >> 2;            // staging row 0..63 (+64 on 2nd rep)
  int scol = (tid & 3) << 4;      // staging col 0,16,32,48

  const short* a0 = Xg + (size_t)(pr0 + srow) * DM + scol;
  const short* a1 = Xg + (size_t)(pr0 + 64 + srow) * DM + scol;
  const short* b0 = W + (size_t)(n0 + srow) * DM + scol;
  const short* b1 = W + (size_t)(n0 + 64 + srow) * DM + scol;

  f32x4 acc[4][4];
  #pragma unroll
  for (int mi = 0; mi < 4; ++mi)
    #pragma unroll
    for (int ni = 0; ni < 4; ++ni) acc[mi][ni] = (f32x4){0.f, 0.f, 0.f, 0.f};

  bf16x8 ra[4], rb[4];
  ra[0] = *(const bf16x8*)(a0);     ra[1] = *(const bf16x8*)(a0 + 8);
  ra[2] = *(const bf16x8*)(a1);     ra[3] = *(const bf16x8*)(a1 + 8);
  rb[0] = *(const bf16x8*)(b0);     rb[1] = *(const bf16x8*)(b0 + 8);
  rb[2] = *(const bf16x8*)(b1);     rb[3] = *(const bf16x8*)(b1 + 8);

  for (int k0 = 0; k0 < DM; k0 += 64) {
    *(bf16x8*)&As[srow * GP + scol]            = ra[0];
    *(bf16x8*)&As[srow * GP + scol + 8]        = ra[1];
    *(bf16x8*)&As[(64 + srow) * GP + scol]     = ra[2];
    *(bf16x8*)&As[(64 + srow) * GP + scol + 8] = ra[3];
    *(bf16x8*)&Bs[srow * GP + scol]            = rb[0];
    *(bf16x8*)&Bs[srow * GP + scol + 8]        = rb[1];
    *(bf16x8*)&Bs[(64 + srow) * GP + scol]     = rb[2];
    *(bf16x8*)&Bs[(64 + srow) * GP + scol + 8] = rb[3];
    __syncthreads();
    if (k0 + 64 < DM) {
      int kn = k0 + 64;
      ra[0] = *(const bf16x8*)(a0 + kn);     ra[1] = *(const bf16x8*)(a0 + kn + 8);
      ra[2] = *(const bf16x8*)(a1 + kn);     ra[3] = *(const bf16x8*)(a1 + kn + 8);
      rb[0] = *(const bf16x8*)(b0 + kn);     rb[1] = *(const bf16x8*)(b0 + kn + 8);
      rb[2] = *(const bf16x8*)(b1 + kn);     rb[3] = *(const bf16x8*)(b1 + kn + 8);
    }
    #pragma unroll
    for (int ks = 0; ks < 2; ++ks) {
      bf16x8 a[4], b[4];
      #pragma unroll
      for (int mi = 0; mi < 4; ++mi)
        a[mi] = *(bf16x8*)&As[(wm * 64 + mi * 16 + col) * GP + ks * 32 + (quad << 3)];
      #pragma unroll
      for (int ni = 0; ni < 4; ++ni)
        b[ni] = *(bf16x8*)&Bs[(wn * 64 + ni * 16 + col) * GP + ks * 32 + (quad << 3)];
      #pragma unroll
      for (int mi = 0; mi < 4; ++mi)
        #pragma unroll
        for (int ni = 0; ni < 4; ++ni)
          acc[mi][ni] = __builtin_amdgcn_mfma_f32_16x16x32_bf16(a[mi], b[ni], acc[mi][ni], 0, 0, 0);
    }
    __syncthreads();
  }

  float scale = (bx < 8) ? (0.125f * 1.44269504f) : 1.0f;
  const float* bias = bqkv + lab * QKV_C;
  #pragma unroll
  for (int mi = 0; mi < 4; ++mi) {
    #pragma unroll
    for (int r = 0; r < 4; ++r) {
      int prow = pr0 + wm * 64 + mi * 16 + (quad << 2) + r;
      int t2 = rowmap[prow];
      if (t2 < 0) continue;
      #pragma unroll
      for (int ni = 0; ni < 4; ++ni) {
        int gn = n0 + wn * 64 + ni * 16 + col;
        float v = (acc[mi][ni][r] + bias[gn]) * scale;
        qkvb[(size_t)t2 * QKV_C + gn] = f2bf(v);
      }
    }
  }
}

// ---------------- kernel 3b: V transpose  qkvb V-region -> VT[b][h][d][n] ----
__global__ __launch_bounds__(256) void vtb_k(const short* __restrict__ qkvb,
                                             short* __restrict__ VTg) {
  __shared__ short T[64 * GP];
  int n0 = blockIdx.x * 64, h = blockIdx.y, b = blockIdx.z;
  int tid = threadIdx.x;
  int r = tid >> 2, cb = tid & 3;
  {
    const short* src = qkvb + ((size_t)(b * SEQ + n0 + r)) * QKV_C + 2 * DP + h * DH + (cb << 4);
    int scc = ((cb + (r >> 4)) & 3) << 4;   // rotated chunk
    *(bf16x8*)&T[r * GP + scc]     = *(const bf16x8*)(src);
    *(bf16x8*)&T[r * GP + scc + 8] = *(const bf16x8*)(src + 8);
  }
  __syncthreads();
  int d = tid >> 2, nc = (tid & 3) << 4;
  int sc2 = (((d >> 4) + (nc >> 4)) & 3) << 4;
  short tmp[16];
  #pragma unroll
  for (int j = 0; j < 16; ++j) tmp[j] = T[(nc + j) * GP + sc2 + (d & 15)];
  short* dst = VTg + ((size_t)(b * NH + h) * DH + d) * SEQ + n0 + nc;
  *(bf16x8*)&dst[0] = *(bf16x8*)&tmp[0];
  *(bf16x8*)&dst[8] = *(bf16x8*)&tmp[8];
}

// ---------------- kernel 4: flash attention, bf16 MFMA, bf16 I/O -----------
// v13: QBLK=256, 8 waves/block (512 threads). Per-wave math identical to the
// verified v12; K/V staged once per 256 q-rows (staging loads, ds_writes and
// barriers HALVE per unit work). LDS 55.3KB -> 2 blocks/CU x 8 waves = same
// 16 waves/CU occupancy; 512 blocks cover all CUs.
__global__ __launch_bounds__(512) void attn_k(short* __restrict__ qkvb,
                                              const short* __restrict__ VTg) {
  int qt = blockIdx.x, h = blockIdx.y, b = blockIdx.z;
  __shared__ short Ks[64 * GP];
  __shared__ short VT[64 * GP];    // VT[d][kv]
  __shared__ short Ps[256 * GP];   // [q 0..255][kv 0..63]

  int tid  = threadIdx.x;
  int lane = tid & 63;
  int w    = tid >> 6;             // 0..7
  int col  = lane & 15;
  int quad = lane >> 4;

  size_t rowbase = (size_t)b * SEQ;
  int hoff = h * DH;
  int sr = tid >> 3;            // staging row 0..63
  int sc = (tid & 7) << 3;      // staging col 0,8,..,56 (16B per thread)

  const short* ksrc = qkvb + (rowbase + sr) * QKV_C + DP + hoff + sc;
  const short* vsrc = VTg + ((size_t)(b * NH + h) * DH + sr) * SEQ + sc;

  // ---- Q B-fragments: direct global load, loop-invariant (2 strips) ----
  bf16x8 qf0[2], qf1[2];
  {
    const short* q0 = qkvb + (rowbase + qt * 256 + (w << 4) + col) * QKV_C + hoff + (quad << 3);
    const short* q1 = q0 + (size_t)128 * QKV_C;
    qf0[0] = *(const bf16x8*)(q0);
    qf0[1] = *(const bf16x8*)(q0 + 32);
    qf1[0] = *(const bf16x8*)(q1);
    qf1[1] = *(const bf16x8*)(q1 + 32);
  }

  // ---- preload kv tile 0 ----
  {
    bf16x8 ka = *(const bf16x8*)(ksrc);
    bf16x8 va = *(const bf16x8*)(vsrc);
    *(bf16x8*)&Ks[sr * GP + sc] = ka;
    *(bf16x8*)&VT[sr * GP + sc] = va;
  }
  __syncthreads();

  float m_0 = -1e30f, l_0 = 0.f, m_1 = -1e30f, l_1 = 0.f;
  f32x4 o0[4], o1[4];   // O^T: lane holds O[q=col][d = nd*16 + quad*4 + r]
  #pragma unroll
  for (int nd = 0; nd < 4; ++nd) {
    o0[nd] = (f32x4){0.f, 0.f, 0.f, 0.f};
    o1[nd] = (f32x4){0.f, 0.f, 0.f, 0.f};
  }

  short* ps0 = &Ps[((w << 4) + col) * GP];
  short* ps1 = &Ps[(128 + (w << 4) + col) * GP];

  auto softmax_strip = [&](f32x4* s, float& m_, float& l_, f32x4* o, short* psrow) {
    // 3-ary max tree over this lane's 16 kv values (v_max3)
    float g0 = max3f(s[0][0], s[0][1], s[0][2]);
    float g1 = max3f(s[0][3], s[1][0], s[1][1]);
    float g2 = max3f(s[1][2], s[1][3], s[2][0]);
    float g3 = max3f(s[2][1], s[2][2], s[2][3]);
    float g4 = max3f(s[3][0], s[3][1], s[3][2]);
    float mx = fmaxf(max3f(g0, g1, g2), max3f(g3, g4, s[3][3]));
    if (!__all(mx - m_ <= 8.f)) {
      float mxr = fmaxf(mx, __shfl_xor(mx, 16));
      mxr = fmaxf(mxr, __shfl_xor(mxr, 32));
      float mnew  = fmaxf(m_, mxr);
      float alpha = fast_exp2(m_ - mnew);
      l_ *= alpha;
      #pragma unroll
      for (int nd = 0; nd < 4; ++nd)
        #pragma unroll
        for (int r = 0; r < 4; ++r) o[nd][r] *= alpha;
      m_ = mnew;
    }
    float p[4][4];
    #pragma unroll
    for (int nj = 0; nj < 4; ++nj)
      #pragma unroll
      for (int r = 0; r < 4; ++r) p[nj][r] = fast_exp2(s[nj][r] - m_);
    float rs = 0.f;
    #pragma unroll
    for (int nj = 0; nj < 4; ++nj)
      rs += (p[nj][0] + p[nj][1]) + (p[nj][2] + p[nj][3]);
    l_ += rs;            // per-lane partial; cross-quad reduce at epilogue
    #pragma unroll
    for (int nj = 0; nj < 4; ++nj) {
      uint2 u;
      u.x = cvt_pk_bf16(p[nj][0], p[nj][1]);
      u.y = cvt_pk_bf16(p[nj][2], p[nj][3]);
      *(uint2*)&psrow[nj * 16 + (quad << 2)] = u;
    }
  };

  auto compute_tile = [&]() {
    f32x4 s0[4], s1[4];
    #pragma unroll
    for (int nj = 0; nj < 4; ++nj) {
      s0[nj] = (f32x4){0.f, 0.f, 0.f, 0.f};
      s1[nj] = (f32x4){0.f, 0.f, 0.f, 0.f};
    }
    __builtin_amdgcn_s_setprio(1);
    #pragma unroll
    for (int ks = 0; ks < 2; ++ks) {
      #pragma unroll
      for (int nj = 0; nj < 4; ++nj) {
        bf16x8 aK = *(bf16x8*)&Ks[((nj << 4) + col) * GP + (ks << 5) + (quad << 3)];
        s0[nj] = __builtin_amdgcn_mfma_f32_16x16x32_bf16(aK, qf0[ks], s0[nj], 0, 0, 0);
        s1[nj] = __builtin_amdgcn_mfma_f32_16x16x32_bf16(aK, qf1[ks], s1[nj], 0, 0, 0);
      }
    }
    __builtin_amdgcn_s_setprio(0);
    softmax_strip(s0, m_0, l_0, o0, ps0);
    softmax_strip(s1, m_1, l_1, o1, ps1);
    __builtin_amdgcn_s_setprio(1);
    #pragma unroll
    for (int ks = 0; ks < 2; ++ks) {
      bf16x8 bP0 = *(bf16x8*)&ps0[(ks << 5) + (quad << 3)];
      bf16x8 bP1 = *(bf16x8*)&ps1[(ks << 5) + (quad << 3)];
      #pragma unroll
      for (int nd = 0; nd < 4; ++nd) {
        bf16x8 aV = *(bf16x8*)&VT[((nd << 4) + col) * GP + (ks << 5) + (quad << 3)];
        o0[nd] = __builtin_amdgcn_mfma_f32_16x16x32_bf16(aV, bP0, o0[nd], 0, 0, 0);
        o1[nd] = __builtin_amdgcn_mfma_f32_16x16x32_bf16(aV, bP1, o1[nd], 0, 0, 0);
      }
    }
    __builtin_amdgcn_s_setprio(0);
  };

  for (int kt = 0; kt < SEQ / 64 - 1; ++kt) {
    const short* kn = ksrc + (size_t)(kt + 1) * 64 * QKV_C;
    const short* vn = vsrc + (size_t)(kt + 1) * 64;
    bf16x8 ka = *(const bf16x8*)(kn);
    bf16x8 va = *(const bf16x8*)(vn);

    compute_tile();
    __syncthreads();                   // all waves done reading Ks/VT
    *(bf16x8*)&Ks[sr * GP + sc] = ka;
    *(bf16x8*)&VT[sr * GP + sc] = va;
    __syncthreads();                   // next tile staged
  }
  compute_tile();                      // last tile

  // ---- epilogue: final cross-quad l reduce, O/l packed 8B stores ----
  float lt0 = l_0 + __shfl_xor(l_0, 16);
  lt0 += __shfl_xor(lt0, 32);
  float lt1 = l_1 + __shfl_xor(l_1, 16);
  lt1 += __shfl_xor(lt1, 32);
  #pragma unroll
  for (int s = 0; s < 2; ++s) {
    float inv = 1.f / (s ? lt1 : lt0);
    f32x4* o = s ? o1 : o0;
    size_t row = rowbase + qt * 256 + s * 128 + (w << 4) + col;
    #pragma unroll
    for (int nd = 0; nd < 4; ++nd) {
      uint2 u;
      u.x = cvt_pk_bf16(o[nd][0] * inv, o[nd][1] * inv);
      u.y = cvt_pk_bf16(o[nd][2] * inv, o[nd][3] * inv);
      *(uint2*)(qkvb + row * QKV_C + hoff + (nd << 4) + (quad << 2)) = u;
    }
  }
}

// ---------------- kernel 5: output projection, bf16 MFMA ----------------
__global__ __launch_bounds__(256) void proj_mfma_k(
    const short* __restrict__ Ab, const short* __restrict__ Wt,
    const float* __restrict__ bias, float* __restrict__ out) {
  __shared__ short As[128 * GP];
  __shared__ short Bs[128 * GP];
  int flat = blockIdx.y * 8 + blockIdx.x;
  int swz  = (flat & 7) * 64 + (flat >> 3);
  int n0 = (swz & 7) * 128, m0 = (swz >> 3) * 128;

  int tid  = threadIdx.x;
  int lane = tid & 63, w = tid >> 6;
  int wm = w >> 1, wn = w & 1;
  int col = lane & 15, quad = lane >> 4;
  int srow = tid >> 2;
  int scol = (tid & 3) << 4;

  const short* a0 = Ab + (size_t)(m0 + srow) * QKV_C + scol;
  const short* a1 = Ab + (size_t)(m0 + 64 + srow) * QKV_C + scol;
  const short* b0 = Wt + (size_t)(n0 + srow) * DP + scol;
  const short* b1 = Wt + (size_t)(n0 + 64 + srow) * DP + scol;

  f32x4 acc[4][4];
  #pragma unroll
  for (int mi = 0; mi < 4; ++mi)
    #pragma unroll
    for (int ni = 0; ni < 4; ++ni) acc[mi][ni] = (f32x4){0.f, 0.f, 0.f, 0.f};

  bf16x8 ra[4], rb[4];
  ra[0] = *(const bf16x8*)(a0);     ra[1] = *(const bf16x8*)(a0 + 8);
  ra[2] = *(const bf16x8*)(a1);     ra[3] = *(const bf16x8*)(a1 + 8);
  rb[0] = *(const bf16x8*)(b0);     rb[1] = *(const bf16x8*)(b0 + 8);
  rb[2] = *(const bf16x8*)(b1);     rb[3] = *(const bf16x8*)(b1 + 8);

  for (int k0 = 0; k0 < DP; k0 += 64) {
    *(bf16x8*)&As[srow * GP + scol]            = ra[0];
    *(bf16x8*)&As[srow * GP + scol + 8]        = ra[1];
    *(bf16x8*)&As[(64 + srow) * GP + scol]     = ra[2];
    *(bf16x8*)&As[(64 + srow) * GP + scol + 8] = ra[3];
    *(bf16x8*)&Bs[srow * GP + scol]            = rb[0];
    *(bf16x8*)&Bs[srow * GP + scol + 8]        = rb[1];
    *(bf16x8*)&Bs[(64 + srow) * GP + scol]     = rb[2];
    *(bf16x8*)&Bs[(64 + srow) * GP + scol + 8] = rb[3];
    __syncthreads();
    if (k0 + 64 < DP) {
      int kn = k0 + 64;
      ra[0] = *(const bf16x8*)(a0 + kn);     ra[1] = *(const bf16x8*)(a0 + kn + 8);
      ra[2] = *(const bf16x8*)(a1 + kn);     ra[3] = *(const bf16x8*)(a1 + kn + 8);
      rb[0] = *(const bf16x8*)(b0 + kn);     rb[1] = *(const bf16x8*)(b0 + kn + 8);
      rb[2] = *(const bf16x8*)(b1 + kn);     rb[3] = *(const bf16x8*)(b1 + kn + 8);
    }
    #pragma unroll
    for (int ks = 0; ks < 2; ++ks) {
      bf16x8 a[4], b[4];
      #pragma unroll
      for (int mi = 0; mi < 4; ++mi)
        a[mi] = *(bf16x8*)&As[(wm * 64 + mi * 16 + col) * GP + ks * 32 + (quad << 3)];
      #pragma unroll
      for (int ni = 0; ni < 4; ++ni)
        b[ni] = *(bf16x8*)&Bs[(wn * 64 + ni * 16 + col) * GP + ks * 32 + (quad << 3)];
      #pragma unroll
      for (int mi = 0; mi < 4; ++mi)
        #pragma unroll
        for (int ni = 0; ni < 4; ++ni)
          acc[mi][ni] = __builtin_amdgcn_mfma_f32_16x16x32_bf16(a[mi], b[ni], acc[mi][ni], 0, 0, 0);
    }
    __syncthreads();
  }

  #pragma unroll
  for (int mi = 0; mi < 4; ++mi) {
    #pragma unroll
    for (int r = 0; r < 4; ++r) {
      int m = m0 + wm * 64 + mi * 16 + (quad << 2) + r;
      #pragma unroll
      for (int ni = 0; ni < 4; ++ni) {
        int gn = n0 + wn * 64 + ni * 16 + col;
        out[(size_t)m * DM + gn] = acc[mi][ni][r] + bias[gn];
      }
    }
  }
}

// ---------------- launch ----------------
extern "C" void kernel_launch(void* const* d_in, const int* in_sizes, int n_in,
                              void* d_out, int out_size, void* d_ws, size_t ws_size,
                              hipStream_t stream) {
  (void)in_sizes; (void)n_in; (void)out_size; (void)ws_size;
  const float* X     = (const float*)d_in[0];
  const int*   L     = (const int*)d_in[1];
  const float* Wqkv  = (const float*)d_in[2];
  const float* bqkv  = (const float*)d_in[3];
  const float* Wproj = (const float*)d_in[4];
  const float* bproj = (const float*)d_in[5];
  float* out = (float*)d_out;

  char* ws = (char*)d_ws;
  short* qkvb    = (short*)ws;                                   // 8192x3072 bf16 (50.3 MB)
  short* Wqkv_t  = (short*)(ws + (size_t)TOK * QKV_C * 2);       // 8x3072x1024 bf16 (50.3 MB)
  short* Wproj_t = (short*)(ws + (size_t)TOK * QKV_C * 2
                               + (size_t)NLAB * QKV_C * DM * 2); // 1024x1024 bf16 (2.1 MB)
  int* sorted = (int*)((char*)Wproj_t + (size_t)DP * DM * 2);
  int* rowmap = sorted + TOK;
  short* Xg = (short*)(rowmap + PROWS);                          // 9216x1024 bf16 (18.9 MB)
  // VT[b][h][d][n] bf16 (16.8 MB) aliases Wqkv_t, which is dead after
  // qkv_mfma_k and re-built by prep_k at the start of each iteration.
  short* VTg = Wqkv_t;

  build_lists_k<<<dim3(1), dim3(256), 0, stream>>>(L, sorted, rowmap);
  prep_k<<<dim3(PROWS + 6144 + 256), dim3(256), 0, stream>>>(
      X, rowmap, Xg, Wqkv, Wqkv_t, Wproj, Wproj_t);
  qkv_mfma_k<<<dim3(QKV_C / 128, PROWS / 128), dim3(256), 0, stream>>>(
      Xg, Wqkv_t, bqkv, rowmap, qkvb);
  vtb_k<<<dim3(SEQ / 64, NH, BATCH), dim3(256), 0, stream>>>(qkvb, VTg);
  attn_k<<<dim3(SEQ / 256, NH, BATCH), dim3(512), 0, stream>>>(qkvb, VTg);
  proj_mfma_k<<<dim3(DM / 128, TOK / 128), dim3(256), 0, stream>>>(
      qkvb, Wproj_t, bproj, out);
}